// Round 5
// baseline (366.087 us; speedup 1.0000x reference)
//
#include <hip/hip_runtime.h>
#include <math.h>

// Problem constants (B=1)
#define LSEQ 1024
#define DM   1024
#define NH   16
#define HD   64
#define KEXP 8
#define NC   16   // chunks
#define CH   64   // chunk length
#define EPSF 1e-5f
#define PD   68   // LDS row pad (words) for attn kernels
#define WPD  65

typedef unsigned short u16;
typedef unsigned int   u32;
typedef __attribute__((ext_vector_type(8))) short short8;   // 8 bf16 (4 VGPRs)
typedef __attribute__((ext_vector_type(4))) float f32x4;

__device__ __forceinline__ u16 f2bf(float f) {
    u32 u = __float_as_uint(f);
    return (u16)((u + 0x7fffu + ((u >> 16) & 1u)) >> 16);   // RNE
}
__device__ __forceinline__ float bf2f(u16 h) {
    return __uint_as_float(((u32)h) << 16);
}

// ---------------- conv (depthwise-expand, k=3, pad (2,0)) + (K,H,h) reorder → bf16 hi/lo ----------------
__global__ __launch_bounds__(256) void conv_reorder(const float* __restrict__ x,
        const float* __restrict__ cw, const float* __restrict__ cb,
        u16* __restrict__ xrh, u16* __restrict__ xrl) {
    int g = blockIdx.x * 256 + threadIdx.x;   // [0, L*DM)
    int t = g >> 10;
    int d = g & 1023;
    float x0 = (t >= 2) ? x[(size_t)(t-2)*DM + d] : 0.f;
    float x1 = (t >= 1) ? x[(size_t)(t-1)*DM + d] : 0.f;
    float x2 = x[(size_t)t*DM + d];
    #pragma unroll
    for (int kk = 0; kk < KEXP; ++kk) {
        int o = d*KEXP + kk;
        float r = x0*cw[o*3+0] + x1*cw[o*3+1] + x2*cw[o*3+2] + cb[o];
        size_t oo = (size_t)t*(DM*KEXP) + kk*DM + d;
        u16 h = f2bf(r);
        xrh[oo] = h;
        xrl[oo] = f2bf(r - bf2f(h));
    }
}

// ---------------- tiled transpose + bf16 hi/lo split: W[R][C] -> T[C][R] ----------------
__global__ __launch_bounds__(256) void wconv_t(const float* __restrict__ W,
        u16* __restrict__ Th, u16* __restrict__ Tl, int R, int C) {
    __shared__ float t[32][33];
    int c0 = blockIdx.x*32, r0 = blockIdx.y*32;
    int tx = threadIdx.x & 31, ty = threadIdx.x >> 5;   // ty 0..7
    #pragma unroll
    for (int k2 = 0; k2 < 4; ++k2)
        t[ty+8*k2][tx] = W[(size_t)(r0+ty+8*k2)*C + c0+tx];
    __syncthreads();
    #pragma unroll
    for (int k2 = 0; k2 < 4; ++k2) {
        float v = t[tx][ty+8*k2];
        u16 h = f2bf(v);
        size_t o = (size_t)(c0+ty+8*k2)*R + r0+tx;
        Th[o] = h;
        Tl[o] = f2bf(v - bf2f(h));
    }
}

// ---------------- 128x128-tile split-K MFMA GEMM (bf16 hi/lo ×3 passes), fp32 partials ----------------
// grid (N/128, M/128, Z), 512 threads (8 waves, 2m x 4n), BK=64.
// Requires (gridDim.x*gridDim.y) % 8 == 0; id%gridDim.y -> m so XCD i%8 owns one m-panel (A L2-hot).
// LDS staging: chunk c -> row c>>3, slot (c + (c>>3))&7  => (row+slot)%8 uniform per wave
// => conflict-free ds_write_b128; reads (fr+kh)%8 uniform => conflict-free ds_read_b128.
__global__ __launch_bounds__(512, 4) void gemm_bf16x3_128(
        const u16* __restrict__ Ah, const u16* __restrict__ Al,
        const u16* __restrict__ Bth, const u16* __restrict__ Btl,
        float* __restrict__ Cp, int M, int N, int K) {
    __shared__ u16 Ash[128][72];
    __shared__ u16 Asl[128][72];
    __shared__ u16 Bsh[128][72];
    __shared__ u16 Bsl[128][72];

    const int tid = threadIdx.x;
    const int z = blockIdx.z, Z = gridDim.z;
    const int id = blockIdx.y * gridDim.x + blockIdx.x;
    const int gy = gridDim.y;
    const int m0 = (id % gy) * 128;
    const int n0 = (id / gy) * 128;
    const int lane = tid & 63, w = tid >> 6;
    const int wm = w >> 2, wn = w & 3;
    const int fr = lane & 15, kh = lane >> 4;

    // staging chunks: c0 = tid (rows 0..63), c1 = tid+512 (rows 64..127); same slot
    const int r0 = tid >> 3;
    const int sl = (tid + (tid >> 3)) & 7;
    const int sc = sl * 8;                      // u16 col
    const size_t aO0 = (size_t)(m0 + r0)      * K + sc;
    const size_t aO1 = (size_t)(m0 + r0 + 64) * K + sc;
    const size_t bO0 = (size_t)(n0 + r0)      * K + sc;
    const size_t bO1 = (size_t)(n0 + r0 + 64) * K + sc;

    const int ktiles = K >> 6;
    const int t0 = (ktiles * z) / Z, t1 = (ktiles * (z + 1)) / Z;

    uint4 ra0h, ra0l, ra1h, ra1l, rb0h, rb0l, rb1h, rb1l;
    f32x4 acc[4][2];
    #pragma unroll
    for (int mi = 0; mi < 4; ++mi)
        #pragma unroll
        for (int ni = 0; ni < 2; ++ni) acc[mi][ni] = (f32x4){0,0,0,0};

#define LOADG128(t_) { size_t ko_ = (size_t)(t_) * 64;                  \
        ra0h = *(const uint4*)(Ah  + aO0 + ko_);                        \
        ra0l = *(const uint4*)(Al  + aO0 + ko_);                        \
        ra1h = *(const uint4*)(Ah  + aO1 + ko_);                        \
        ra1l = *(const uint4*)(Al  + aO1 + ko_);                        \
        rb0h = *(const uint4*)(Bth + bO0 + ko_);                        \
        rb0l = *(const uint4*)(Btl + bO0 + ko_);                        \
        rb1h = *(const uint4*)(Bth + bO1 + ko_);                        \
        rb1l = *(const uint4*)(Btl + bO1 + ko_); }
#define WRLDS128() {                                                    \
        *(uint4*)&Ash[r0   ][sc] = ra0h; *(uint4*)&Asl[r0   ][sc] = ra0l; \
        *(uint4*)&Ash[r0+64][sc] = ra1h; *(uint4*)&Asl[r0+64][sc] = ra1l; \
        *(uint4*)&Bsh[r0   ][sc] = rb0h; *(uint4*)&Bsl[r0   ][sc] = rb0l; \
        *(uint4*)&Bsh[r0+64][sc] = rb1h; *(uint4*)&Bsl[r0+64][sc] = rb1l; }
#define MF(a_,b_,c_) c_ = __builtin_amdgcn_mfma_f32_16x16x32_bf16(a_, b_, c_, 0, 0, 0)

    LOADG128(t0);
    WRLDS128();
    __syncthreads();

    for (int t = t0; t < t1; ++t) {
        if (t + 1 < t1) LOADG128(t + 1);
        #pragma unroll
        for (int ks = 0; ks < 2; ++ks) {
            const int ko = ks*32 + kh*8;
            short8 a_h[4], a_l[4], b_h[2], b_l[2];
            #pragma unroll
            for (int mi = 0; mi < 4; ++mi) {
                a_h[mi] = *(const short8*)&Ash[wm*64 + mi*16 + fr][ko];
                a_l[mi] = *(const short8*)&Asl[wm*64 + mi*16 + fr][ko];
            }
            #pragma unroll
            for (int ni = 0; ni < 2; ++ni) {
                b_h[ni] = *(const short8*)&Bsh[wn*32 + ni*16 + fr][ko];
                b_l[ni] = *(const short8*)&Bsl[wn*32 + ni*16 + fr][ko];
            }
            #pragma unroll
            for (int mi = 0; mi < 4; ++mi)
                #pragma unroll
                for (int ni = 0; ni < 2; ++ni) {
                    MF(a_h[mi], b_h[ni], acc[mi][ni]);
                    MF(a_h[mi], b_l[ni], acc[mi][ni]);
                    MF(a_l[mi], b_h[ni], acc[mi][ni]);
                }
        }
        __syncthreads();
        if (t + 1 < t1) {
            WRLDS128();
            __syncthreads();
        }
    }
#undef MF
#undef LOADG128
#undef WRLDS128

    float* Cz = Cp + (size_t)z * M * N;
    #pragma unroll
    for (int mi = 0; mi < 4; ++mi)
        #pragma unroll
        for (int ni = 0; ni < 2; ++ni) {
            const int col = n0 + wn*32 + ni*16 + fr;
            #pragma unroll
            for (int rr = 0; rr < 4; ++rr) {
                const int row = m0 + wm*64 + mi*16 + kh*4 + rr;
                Cz[(size_t)row * N + col] = acc[mi][ni][rr];
            }
        }
}

// ---------------- reduce 8 partials + bias -> xt hi/lo ----------------
__global__ __launch_bounds__(256) void reduce_xt8(const float* __restrict__ Cp,
        const float* __restrict__ bias, u16* __restrict__ xh, u16* __restrict__ xl) {
    int g = blockIdx.x * 256 + threadIdx.x;   // 262144
    int idx = g * 4;
    float4 bv = *(const float4*)(bias + (idx & 1023));
    float v[4] = {bv.x, bv.y, bv.z, bv.w};
    #pragma unroll
    for (int s = 0; s < 8; ++s) {
        float4 a = *(const float4*)(Cp + (size_t)s*1048576 + idx);
        v[0] += a.x; v[1] += a.y; v[2] += a.z; v[3] += a.w;
    }
    ushort4 hh, ll;
    u16* hp = (u16*)&hh; u16* lp = (u16*)&ll;
    #pragma unroll
    for (int j = 0; j < 4; ++j) {
        u16 h = f2bf(v[j]);
        hp[j] = h;
        lp[j] = f2bf(v[j] - bf2f(h));
    }
    *(ushort4*)(xh + idx) = hh;
    *(ushort4*)(xl + idx) = ll;
}

// ---------------- reduce QKV partials (2 x 1024x3072) + bias + per-head normalize ----------------
__global__ __launch_bounds__(256) void reduce_qkv(const float* __restrict__ Cp,
        const float* __restrict__ qbias, const float* __restrict__ kbias,
        const float* __restrict__ vbias,
        float* __restrict__ qo, float* __restrict__ ko, float* __restrict__ vo) {
    int row = blockIdx.x;             // 0..1023
    int t = threadIdx.x;              // 0..255; cols t*4 (within proj), head = t/16
    const float* biases[3] = {qbias, kbias, vbias};
    float* outs[3] = {qo, ko, vo};
    int col = t * 4;
    #pragma unroll
    for (int s = 0; s < 3; ++s) {
        size_t o = (size_t)row*3072 + (size_t)s*1024 + col;
        float4 a = *(const float4*)(Cp + o);
        float4 b = *(const float4*)(Cp + 3145728 + o);
        float4 bv = *(const float4*)(biases[s] + col);
        float v0 = a.x + b.x + bv.x, v1 = a.y + b.y + bv.y;
        float v2 = a.z + b.z + bv.z, v3 = a.w + b.w + bv.w;
        float ss = v0*v0 + v1*v1 + v2*v2 + v3*v3;
        #pragma unroll
        for (int off = 1; off < 16; off <<= 1) ss += __shfl_xor(ss, off);
        float scl = 1.0f / fmaxf(sqrtf(ss), 1e-12f);
        float4 o4 = {v0*scl, v1*scl, v2*scl, v3*scl};
        *(float4*)(outs[s] + (size_t)row*1024 + col) = o4;
    }
}

// ---------------- reduce 8 partials, apply rowscale + bias -> fp32 out ----------------
__global__ __launch_bounds__(256) void reduce_out8(const float* __restrict__ Cp,
        const float* __restrict__ rowscale, const float* __restrict__ bias,
        float* __restrict__ out) {
    int g = blockIdx.x * 256 + threadIdx.x;   // 262144
    int idx = g * 4;
    float s0 = 0.f, s1 = 0.f, s2 = 0.f, s3 = 0.f;
    #pragma unroll
    for (int s = 0; s < 8; ++s) {
        float4 a = *(const float4*)(Cp + (size_t)s*1048576 + idx);
        s0 += a.x; s1 += a.y; s2 += a.z; s3 += a.w;
    }
    float4 bv = *(const float4*)(bias + (idx & 1023));
    float rs = rowscale[idx >> 10];
    float4 o = {s0*rs + bv.x, s1*rs + bv.y, s2*rs + bv.z, s3*rs + bv.w};
    *(float4*)(out + idx) = o;
}

// ---------------- attention: per-(head,chunk) locals ----------------
__global__ __launch_bounds__(256) void attn_local(const float* __restrict__ qb,
        const float* __restrict__ kb, const float* __restrict__ vb,
        const float* __restrict__ wgz_w, const float* __restrict__ wgz_b,
        const float* __restrict__ kv_scale, const float* __restrict__ qk_scale,
        float* __restrict__ simG, float* __restrict__ gateG,
        float* __restrict__ Sloc, float* __restrict__ nloc, float* __restrict__ aggL) {
    int c = blockIdx.x, h = blockIdx.y;
    int tid = threadIdx.x;
    __shared__ float q_l[CH][PD], k_l[CH][PD], v_l[CH][PD];
    __shared__ float wg_l[HD][WPD];
    __shared__ float sim_s[CH], gate_s[CH], e_s[CH];

    for (int idx = tid; idx < CH*HD; idx += 256) {
        int i = idx >> 6, d = idx & 63;
        size_t gp = (size_t)(c*CH + i)*DM + h*HD + d;
        q_l[i][d] = qb[gp]; k_l[i][d] = kb[gp]; v_l[i][d] = vb[gp];
        wg_l[i][d] = wgz_w[idx];   // i==p, d==n
    }
    __syncthreads();

    int si = tid >> 2, part = tid & 3;
    float qk_h = qk_scale[h];
    float kv0  = kv_scale[0];

    float sum = 0.f;
    #pragma unroll
    for (int d = 0; d < 16; ++d) sum += q_l[si][part*16+d]*k_l[si][part*16+d];
    sum += __shfl_xor(sum, 1); sum += __shfl_xor(sum, 2);

    float gpart = 0.f;
    for (int pp = 0; pp < 16; ++pp) {
        int p = part*16 + pp;
        float u = 0.f;
        for (int n = 0; n < 64; ++n) u += wg_l[p][n]*k_l[si][n];
        gpart += v_l[si][p]*u;
    }
    gpart += __shfl_xor(gpart, 1); gpart += __shfl_xor(gpart, 2);

    if (part == 0) {
        sim_s[si] = sum * qk_h;
        float raw = kv0*gpart + wgz_b[0];
        gate_s[si] = ((raw > 0.f) ? raw : 0.01f*raw) + EPSF;
    }
    __syncthreads();

    if (tid < CH) {
        simG[h*LSEQ + c*CH + tid]  = sim_s[tid];
        gateG[h*LSEQ + c*CH + tid] = gate_s[tid];
    }

    {
        int p = tid >> 2, nq = tid & 3;
        float acc[16];
        #pragma unroll
        for (int j = 0; j < 16; ++j) acc[j] = 0.f;
        for (int s = 0; s < CH; ++s) {
            float gv = gate_s[s]*v_l[s][p];
            #pragma unroll
            for (int j = 0; j < 16; ++j) acc[j] += gv * k_l[s][nq*16+j];
        }
        size_t so = ((size_t)h*NC + c)*4096 + (size_t)p*64 + nq*16;
        #pragma unroll
        for (int j = 0; j < 16; ++j) Sloc[so+j] = acc[j];
    }

    float m_loc = -INFINITY, s_loc = 0.f, g_sum = 0.f;
    if (tid < 64) {
        float mv = sim_s[tid];
        m_loc = mv;
        #pragma unroll
        for (int off = 32; off >= 1; off >>= 1) m_loc = fmaxf(m_loc, __shfl_xor(m_loc, off));
        float e = expf(mv - m_loc);
        e_s[tid] = e;
        s_loc = e;
        #pragma unroll
        for (int off = 32; off >= 1; off >>= 1) s_loc += __shfl_xor(s_loc, off);
        float gv = gate_s[tid];
        g_sum = gv;
        #pragma unroll
        for (int off = 32; off >= 1; off >>= 1) g_sum += __shfl_xor(g_sum, off);
    }
    __syncthreads();
    if (tid < 64) {
        float nl = 0.f;
        for (int s = 0; s < CH; ++s) nl += e_s[s]*v_l[s][tid];
        nloc[((size_t)h*NC + c)*64 + tid] = nl;
        if (tid == 0) {
            size_t ao = ((size_t)h*NC + c)*4;
            aggL[ao+0] = m_loc; aggL[ao+1] = s_loc; aggL[ao+2] = g_sum;
        }
    }
}

// ---------------- per-head prefix over chunks (exclusive) ----------------
__global__ __launch_bounds__(256) void attn_prefix(const float* __restrict__ Sloc,
        const float* __restrict__ nloc, const float* __restrict__ aggL,
        float* __restrict__ Spre, float* __restrict__ npre, float* __restrict__ aggP) {
    int h = blockIdx.x;
    int tid = threadIdx.x;
    float S_reg[16];
    #pragma unroll
    for (int j = 0; j < 16; ++j) S_reg[j] = 0.f;
    float n_run = 0.f;
    float m_run = -INFINITY, s_run = 0.f, g_run = 0.f;
    for (int c = 0; c < NC; ++c) {
        size_t base = (size_t)h*NC + c;
        size_t so = base*4096 + (size_t)tid*16;
        #pragma unroll
        for (int j = 0; j < 16; ++j) Spre[so+j] = S_reg[j];
        if (tid < 64) npre[base*64 + tid] = n_run;
        if (tid == 0) { aggP[base*4+0] = m_run; aggP[base*4+1] = s_run; aggP[base*4+2] = g_run; }
        float m_l = aggL[base*4+0], s_l = aggL[base*4+1], g_l = aggL[base*4+2];
        float m_new = fmaxf(m_run, m_l);
        float e1 = expf(m_run - m_new), e2 = expf(m_l - m_new);
        s_run = s_run*e1 + s_l*e2;
        g_run += g_l;
        if (tid < 64) n_run = n_run*e1 + nloc[base*64 + tid]*e2;
        #pragma unroll
        for (int j = 0; j < 16; ++j) S_reg[j] += Sloc[so+j];
        m_run = m_new;
    }
}

// ---------------- per-(head,chunk) outputs (+ bf16 hi/lo of Y for final GEMM) ----------------
__global__ __launch_bounds__(256) void attn_out(const float* __restrict__ qb,
        const float* __restrict__ kb, const float* __restrict__ vb,
        const float* __restrict__ simG, const float* __restrict__ gateG,
        const float* __restrict__ Spre, const float* __restrict__ npre,
        const float* __restrict__ aggP, const float* __restrict__ kv_scale,
        float* __restrict__ Y, u16* __restrict__ yh, u16* __restrict__ yl) {
    int c = blockIdx.x, h = blockIdx.y;
    int tid = threadIdx.x;
    __shared__ float q_l[CH][PD], k_l[CH][PD], v_l[CH][PD], sp_l[HD][PD];
    __shared__ float a_l[CH][PD], m_l[CH][PD];
    __shared__ float sim_s[CH], gate_s[CH], mc_s[CH], ep_s[CH], gc_s[CH],
                     sc_s[CH], w_s2[CH], qs_s[CH], np_l[HD];
    size_t base = (size_t)h*NC + c;

    for (int idx = tid; idx < CH*HD; idx += 256) {
        int i = idx >> 6, d = idx & 63;
        size_t gp = (size_t)(c*CH + i)*DM + h*HD + d;
        q_l[i][d] = qb[gp]; k_l[i][d] = kb[gp]; v_l[i][d] = vb[gp];
        sp_l[i][d] = Spre[base*4096 + idx];
    }
    if (tid < CH) {
        sim_s[tid]  = simG[h*LSEQ + c*CH + tid];
        gate_s[tid] = gateG[h*LSEQ + c*CH + tid];
        np_l[tid]   = npre[base*64 + tid];
    }
    __syncthreads();

    float m_p = aggP[base*4+0], s_p = aggP[base*4+1], g_p = aggP[base*4+2];
    float kv0 = kv_scale[0];

    if (tid < CH) {
        int i = tid;
        float mloc = -INFINITY, gcum = 0.f;
        for (int s = 0; s <= i; ++s) { mloc = fmaxf(mloc, sim_s[s]); gcum += gate_s[s]; }
        float mc = fmaxf(m_p, mloc);
        mc_s[i] = mc;
        ep_s[i] = expf(m_p - mc);
        gc_s[i] = g_p + gcum;
        float qs = 0.f;
        for (int d = 0; d < 64; ++d) qs += q_l[i][d];
        qs_s[i] = qs;
    }
    __syncthreads();

    {
        int i = tid >> 2, sq = tid & 3;
        float mci = mc_s[i];
        #pragma unroll
        for (int jj = 0; jj < 16; ++jj) {
            int s = sq*16 + jj;
            float Mv = 0.f, Av = 0.f;
            if (s <= i) {
                Mv = expf(sim_s[s] - mci);
                float dot = 0.f;
                #pragma unroll
                for (int dq = 0; dq < 16; ++dq) {
                    float4 q4 = *(const float4*)&q_l[i][dq*4];
                    float4 v4 = *(const float4*)&v_l[s][dq*4];
                    dot += q4.x*v4.x + q4.y*v4.y + q4.z*v4.z + q4.w*v4.w;
                }
                Av = gate_s[s]*dot;
            }
            m_l[i][s] = Mv;
            a_l[i][s] = Av;
        }
    }
    __syncthreads();

    if (tid < CH) {
        int i = tid;
        float rs = 0.f;
        for (int s = 0; s < CH; ++s) rs += m_l[i][s];
        float sc = ep_s[i]*s_p + rs;
        sc_s[i] = sc;
        w_s2[i] = expf(sim_s[i] - mc_s[i]) / (sc + EPSF);
    }
    __syncthreads();

    {
        int i = tid >> 2, nq = tid & 3;
        float yb[16], ncv[16];
        #pragma unroll
        for (int j = 0; j < 16; ++j) { yb[j] = 0.f; ncv[j] = 0.f; }
        for (int p = 0; p < 64; ++p) {
            float qv = q_l[i][p];
            float av = a_l[i][p];
            float mv = m_l[i][p];
            #pragma unroll
            for (int jq = 0; jq < 4; ++jq) {
                float4 sp4 = *(const float4*)&sp_l[p][nq*16 + jq*4];
                float4 k4  = *(const float4*)&k_l[p][nq*16 + jq*4];
                float4 v4  = *(const float4*)&v_l[p][nq*16 + jq*4];
                yb[jq*4+0] += qv*sp4.x + av*k4.x;  ncv[jq*4+0] += mv*v4.x;
                yb[jq*4+1] += qv*sp4.y + av*k4.y;  ncv[jq*4+1] += mv*v4.y;
                yb[jq*4+2] += qv*sp4.z + av*k4.z;  ncv[jq*4+2] += mv*v4.z;
                yb[jq*4+3] += qv*sp4.w + av*k4.w;  ncv[jq*4+3] += mv*v4.w;
            }
        }
        float gsc   = kv0 / (gc_s[i] + EPSF);
        float invsc = 1.0f / (sc_s[i] + EPSF);
        float ep = ep_s[i], wv = w_s2[i], qs = qs_s[i];
        size_t yo = (size_t)(c*CH + i)*DM + h*HD + nq*16;
        #pragma unroll
        for (int j = 0; j < 16; ++j) {
            float Ybase = yb[j] * gsc;
            float lin   = (ep*np_l[nq*16+j] + ncv[j]) * invsc;
            float val = Ybase + (qs*lin - Ybase)*wv;
            Y[yo + j] = val;
            u16 hh = f2bf(val);
            yh[yo + j] = hh;
            yl[yo + j] = f2bf(val - bf2f(hh));
        }
    }
}

// ---------------- row 1/max(||.||,1e-12) over D=1024 ----------------
__global__ __launch_bounds__(256) void rownorm(const float* __restrict__ Y,
        float* __restrict__ rn) {
    int row = blockIdx.x;
    int tid = threadIdx.x;
    float4 v = *(const float4*)&Y[(size_t)row*DM + tid*4];
    float ss = v.x*v.x + v.y*v.y + v.z*v.z + v.w*v.w;
    #pragma unroll
    for (int off = 32; off >= 1; off >>= 1) ss += __shfl_xor(ss, off);
    __shared__ float wsum[4];
    if ((tid & 63) == 0) wsum[tid >> 6] = ss;
    __syncthreads();
    if (tid == 0) {
        float tot = wsum[0] + wsum[1] + wsum[2] + wsum[3];
        rn[row] = 1.0f / fmaxf(sqrtf(tot), 1e-12f);
    }
}

extern "C" void kernel_launch(void* const* d_in, const int* in_sizes, int n_in,
                              void* d_out, int out_size, void* d_ws, size_t ws_size,
                              hipStream_t stream) {
    const float* x      = (const float*)d_in[0];
    const float* conv_w = (const float*)d_in[1];
    const float* conv_b = (const float*)d_in[2];
    const float* mphi_w = (const float*)d_in[3];
    const float* mphi_b = (const float*)d_in[4];
    const float* wq_w   = (const float*)d_in[5];
    const float* wq_b   = (const float*)d_in[6];
    const float* wk_w   = (const float*)d_in[7];
    const float* wk_b   = (const float*)d_in[8];
    const float* wv_w   = (const float*)d_in[9];
    const float* wv_b   = (const float*)d_in[10];
    const float* wo_w   = (const float*)d_in[11];
    const float* wo_b   = (const float*)d_in[12];
    const float* wgz_w  = (const float*)d_in[13];
    const float* wgz_b  = (const float*)d_in[14];
    const float* kv_sc  = (const float*)d_in[15];
    const float* qk_sc  = (const float*)d_in[16];
    float* out = (float*)d_out;

    // ---- workspace layout (1 MB units in comments), peak ~100 MB ----
    char* p = (char*)d_ws;
    u16*  xr_h    = (u16*)p;                      // [0,16)
    u16*  xr_l    = (u16*)(p + 16777216);         // [16,32)
    u16*  mphiT_h = (u16*)(p + 33554432);         // [32,48)
    u16*  mphiT_l = (u16*)(p + 50331648);         // [48,64)
    float* g1Part = (float*)(p + 67108864);       // [64,96)  8 x 4MB
    u16*  xt_h    = (u16*)(p + 100663296);        // [96,98)
    u16*  xt_l    = (u16*)(p + 102760448);        // [98,100)
    // after GEMM1 (xr/mphiT dead):
    u16*  wqkvT_h = (u16*)p;                      // [0,6)   wq|wk|wv rows stacked
    u16*  wqkvT_l = (u16*)(p + 6291456);          // [6,12)
    u16*  woT_h   = (u16*)(p + 12582912);         // [12,14)
    u16*  woT_l   = (u16*)(p + 14680064);         // [14,16)
    float* qkvPart= (float*)(p + 16777216);       // [16,40)  2 x 12MB
    float* qb     = (float*)(p + 67108864);       // [64,68)  (g1Part dead after reduce_xt8)
    float* kb     = (float*)(p + 71303168);       // [68,72)
    float* vb     = (float*)(p + 75497472);       // [72,76)
    float* Sloc   = (float*)(p + 79691776);       // [76,80)
    float* Spre   = (float*)(p + 83886080);       // [80,84)
    float* Ybuf   = (float*)(p + 41943040);       // [40,44)  (qkvPart dead after reduce_qkv)
    u16*  y_h     = (u16*)(p + 46137344);         // [44,46)
    u16*  y_l     = (u16*)(p + 48234496);         // [46,48)
    float* woPart = (float*)(p + 50331648);       // [48,80)  8 x 4MB (after attn)
    char* q2 = p + 88080384;                      // [84,...) small buffers
    float* simG  = (float*)q2; q2 += 65536;
    float* gateG = (float*)q2; q2 += 65536;
    float* nlocp = (float*)q2; q2 += 65536;
    float* nprep = (float*)q2; q2 += 65536;
    float* aggL  = (float*)q2; q2 += 4096;
    float* aggP  = (float*)q2; q2 += 4096;
    float* rn    = (float*)q2; q2 += 4096;

    conv_reorder<<<4096, 256, 0, stream>>>(x, conv_w, conv_b, xr_h, xr_l);
    wconv_t<<<dim3(32, 256), 256, 0, stream>>>(mphi_w, mphiT_h, mphiT_l, 8192, 1024);

    // GEMM1: xt = xr @ mphi (split-K=8, fp32 partials, then reduce + bias + bf16 split)
    gemm_bf16x3_128<<<dim3(8, 8, 8), 512, 0, stream>>>(xr_h, xr_l, mphiT_h, mphiT_l,
            g1Part, 1024, 1024, 8192);
    reduce_xt8<<<1024, 256, 0, stream>>>(g1Part, mphi_b, xt_h, xt_l);

    // weights for QKV (stacked N=3072) and WO; xr/mphiT regions are dead now
    wconv_t<<<dim3(32, 32), 256, 0, stream>>>(wq_w, wqkvT_h,           wqkvT_l,           1024, 1024);
    wconv_t<<<dim3(32, 32), 256, 0, stream>>>(wk_w, wqkvT_h + 1048576, wqkvT_l + 1048576, 1024, 1024);
    wconv_t<<<dim3(32, 32), 256, 0, stream>>>(wv_w, wqkvT_h + 2097152, wqkvT_l + 2097152, 1024, 1024);
    wconv_t<<<dim3(32, 32), 256, 0, stream>>>(wo_w, woT_h, woT_l, 1024, 1024);

    // QKV fused: (1024 x 3072) = xt @ [wq|wk|wv], split-K=2; reduce adds bias + per-head norm
    gemm_bf16x3_128<<<dim3(24, 8, 2), 512, 0, stream>>>(xt_h, xt_l, wqkvT_h, wqkvT_l,
            qkvPart, 1024, 3072, 1024);
    reduce_qkv<<<1024, 256, 0, stream>>>(qkvPart, wq_b, wk_b, wv_b, qb, kb, vb);

    attn_local<<<dim3(NC, NH), 256, 0, stream>>>(qb, kb, vb, wgz_w, wgz_b, kv_sc, qk_sc,
                                                 simG, gateG, Sloc, nlocp, aggL);
    attn_prefix<<<NH, 256, 0, stream>>>(Sloc, nlocp, aggL, Spre, nprep, aggP);
    attn_out<<<dim3(NC, NH), 256, 0, stream>>>(qb, kb, vb, simG, gateG, Spre, nprep, aggP,
                                               kv_sc, Ybuf, y_h, y_l);
    rownorm<<<1024, 256, 0, stream>>>(Ybuf, rn);

    // WO: out = normalize(Y) @ wo + b (split-K=8; rowscale+bias in reduce)
    gemm_bf16x3_128<<<dim3(8, 8, 8), 512, 0, stream>>>(y_h, y_l, woT_h, woT_l,
            woPart, 1024, 1024, 1024);
    reduce_out8<<<1024, 256, 0, stream>>>(woPart, rn, wo_b, out);
}

// Round 6
// 326.215 us; speedup vs baseline: 1.1222x; 1.1222x over previous
//
#include <hip/hip_runtime.h>
#include <math.h>

// Problem constants (B=1)
#define LSEQ 1024
#define DM   1024
#define NH   16
#define HD   64
#define KEXP 8
#define NC   16   // chunks
#define CH   64   // chunk length
#define EPSF 1e-5f
#define PD   68   // LDS row pad (words) for attn kernels
#define WPD  65

typedef unsigned short u16;
typedef unsigned int   u32;
typedef __attribute__((ext_vector_type(8))) short short8;   // 8 bf16 (4 VGPRs)
typedef __attribute__((ext_vector_type(4))) float f32x4;

__device__ __forceinline__ u16 f2bf(float f) {
    u32 u = __float_as_uint(f);
    return (u16)((u + 0x7fffu + ((u >> 16) & 1u)) >> 16);   // RNE
}
__device__ __forceinline__ float bf2f(u16 h) {
    return __uint_as_float(((u32)h) << 16);
}

// ---------------- conv (depthwise-expand, k=3, pad (2,0)) + (K,H,h) reorder → bf16 hi/lo ----------------
__global__ __launch_bounds__(256) void conv_reorder(const float* __restrict__ x,
        const float* __restrict__ cw, const float* __restrict__ cb,
        u16* __restrict__ xrh, u16* __restrict__ xrl) {
    int g = blockIdx.x * 256 + threadIdx.x;   // [0, L*DM)
    int t = g >> 10;
    int d = g & 1023;
    float x0 = (t >= 2) ? x[(size_t)(t-2)*DM + d] : 0.f;
    float x1 = (t >= 1) ? x[(size_t)(t-1)*DM + d] : 0.f;
    float x2 = x[(size_t)t*DM + d];
    #pragma unroll
    for (int kk = 0; kk < KEXP; ++kk) {
        int o = d*KEXP + kk;
        float r = x0*cw[o*3+0] + x1*cw[o*3+1] + x2*cw[o*3+2] + cb[o];
        size_t oo = (size_t)t*(DM*KEXP) + kk*DM + d;
        u16 h = f2bf(r);
        xrh[oo] = h;
        xrl[oo] = f2bf(r - bf2f(h));
    }
}

// ---------------- tiled transpose + bf16 hi/lo split: W[R][C] -> T[C][R] ----------------
__global__ __launch_bounds__(256) void wconv_t(const float* __restrict__ W,
        u16* __restrict__ Th, u16* __restrict__ Tl, int R, int C) {
    __shared__ float t[32][33];
    int c0 = blockIdx.x*32, r0 = blockIdx.y*32;
    int tx = threadIdx.x & 31, ty = threadIdx.x >> 5;   // ty 0..7
    #pragma unroll
    for (int k2 = 0; k2 < 4; ++k2)
        t[ty+8*k2][tx] = W[(size_t)(r0+ty+8*k2)*C + c0+tx];
    __syncthreads();
    #pragma unroll
    for (int k2 = 0; k2 < 4; ++k2) {
        float v = t[tx][ty+8*k2];
        u16 h = f2bf(v);
        size_t o = (size_t)(c0+ty+8*k2)*R + r0+tx;
        Th[o] = h;
        Tl[o] = f2bf(v - bf2f(h));
    }
}

// ---------------- merged 4-weight transpose (1024x1024 each), z picks source/dest ----------------
__global__ __launch_bounds__(256) void wconv_t4(const float* __restrict__ W0,
        const float* __restrict__ W1, const float* __restrict__ W2,
        const float* __restrict__ W3,
        u16* __restrict__ Tqkv_h, u16* __restrict__ Tqkv_l,
        u16* __restrict__ To_h, u16* __restrict__ To_l) {
    __shared__ float t[32][33];
    int z = blockIdx.z;
    const float* W = (z == 0) ? W0 : (z == 1) ? W1 : (z == 2) ? W2 : W3;
    u16* Th = (z < 3) ? Tqkv_h + (size_t)z*1048576 : To_h;
    u16* Tl = (z < 3) ? Tqkv_l + (size_t)z*1048576 : To_l;
    int c0 = blockIdx.x*32, r0 = blockIdx.y*32;
    int tx = threadIdx.x & 31, ty = threadIdx.x >> 5;
    #pragma unroll
    for (int k2 = 0; k2 < 4; ++k2)
        t[ty+8*k2][tx] = W[(size_t)(r0+ty+8*k2)*1024 + c0+tx];
    __syncthreads();
    #pragma unroll
    for (int k2 = 0; k2 < 4; ++k2) {
        float v = t[tx][ty+8*k2];
        u16 h = f2bf(v);
        size_t o = (size_t)(c0+ty+8*k2)*1024 + r0+tx;
        Th[o] = h;
        Tl[o] = f2bf(v - bf2f(h));
    }
}

// ---------------- 128x128-tile split-K MFMA GEMM (bf16 hi/lo ×3 passes), fp32 partials ----------------
// grid (N/128, M/128, Z), 512 threads (8 waves, 2m x 4n), BK=64.
// 8x8 grids use an XCD-rectangle map (XCD = blockIdx.x owns 2 m-panels x 4 n-panels:
// 3MB/z working set < 4MB L2, A reused 4x + B 2x within the XCD). Other grids use
// the column map (id%gy -> m-panel = XCD).
// LDS staging: chunk c -> row c>>3, slot (c + (c>>3))&7 => conflict-free b128 write/read.
__global__ __launch_bounds__(512, 4) void gemm_bf16x3_128(
        const u16* __restrict__ Ah, const u16* __restrict__ Al,
        const u16* __restrict__ Bth, const u16* __restrict__ Btl,
        float* __restrict__ Cp, int M, int N, int K) {
    __shared__ u16 Ash[128][72];
    __shared__ u16 Asl[128][72];
    __shared__ u16 Bsh[128][72];
    __shared__ u16 Bsl[128][72];

    const int tid = threadIdx.x;
    const int z = blockIdx.z, Z = gridDim.z;
    int mpan, npan;
    if (gridDim.x == 8 && gridDim.y == 8) {
        mpan = ((blockIdx.x >> 1) << 1) + (blockIdx.y >> 2);   // XCD rectangle 2m x 4n
        npan = ((blockIdx.x & 1) << 2) + (blockIdx.y & 3);
    } else {
        const int id = blockIdx.y * gridDim.x + blockIdx.x;
        mpan = id % gridDim.y;
        npan = id / gridDim.y;
    }
    const int m0 = mpan * 128, n0 = npan * 128;
    const int lane = tid & 63, w = tid >> 6;
    const int wm = w >> 2, wn = w & 3;
    const int fr = lane & 15, kh = lane >> 4;

    const int r0 = tid >> 3;
    const int sl = (tid + (tid >> 3)) & 7;
    const int sc = sl * 8;                      // u16 col
    const size_t aO0 = (size_t)(m0 + r0)      * K + sc;
    const size_t aO1 = (size_t)(m0 + r0 + 64) * K + sc;
    const size_t bO0 = (size_t)(n0 + r0)      * K + sc;
    const size_t bO1 = (size_t)(n0 + r0 + 64) * K + sc;

    const int ktiles = K >> 6;
    const int t0 = (ktiles * z) / Z, t1 = (ktiles * (z + 1)) / Z;

    uint4 ra0h, ra0l, ra1h, ra1l, rb0h, rb0l, rb1h, rb1l;
    f32x4 acc[4][2];
    #pragma unroll
    for (int mi = 0; mi < 4; ++mi)
        #pragma unroll
        for (int ni = 0; ni < 2; ++ni) acc[mi][ni] = (f32x4){0,0,0,0};

#define LOADG128(t_) { size_t ko_ = (size_t)(t_) * 64;                  \
        ra0h = *(const uint4*)(Ah  + aO0 + ko_);                        \
        ra0l = *(const uint4*)(Al  + aO0 + ko_);                        \
        ra1h = *(const uint4*)(Ah  + aO1 + ko_);                        \
        ra1l = *(const uint4*)(Al  + aO1 + ko_);                        \
        rb0h = *(const uint4*)(Bth + bO0 + ko_);                        \
        rb0l = *(const uint4*)(Btl + bO0 + ko_);                        \
        rb1h = *(const uint4*)(Bth + bO1 + ko_);                        \
        rb1l = *(const uint4*)(Btl + bO1 + ko_); }
#define WRLDS128() {                                                    \
        *(uint4*)&Ash[r0   ][sc] = ra0h; *(uint4*)&Asl[r0   ][sc] = ra0l; \
        *(uint4*)&Ash[r0+64][sc] = ra1h; *(uint4*)&Asl[r0+64][sc] = ra1l; \
        *(uint4*)&Bsh[r0   ][sc] = rb0h; *(uint4*)&Bsl[r0   ][sc] = rb0l; \
        *(uint4*)&Bsh[r0+64][sc] = rb1h; *(uint4*)&Bsl[r0+64][sc] = rb1l; }
#define MF(a_,b_,c_) c_ = __builtin_amdgcn_mfma_f32_16x16x32_bf16(a_, b_, c_, 0, 0, 0)

    LOADG128(t0);
    WRLDS128();
    __syncthreads();

    for (int t = t0; t < t1; ++t) {
        if (t + 1 < t1) LOADG128(t + 1);
        #pragma unroll
        for (int ks = 0; ks < 2; ++ks) {
            const int ko = ks*32 + kh*8;
            short8 a_h[4], a_l[4], b_h[2], b_l[2];
            #pragma unroll
            for (int mi = 0; mi < 4; ++mi) {
                a_h[mi] = *(const short8*)&Ash[wm*64 + mi*16 + fr][ko];
                a_l[mi] = *(const short8*)&Asl[wm*64 + mi*16 + fr][ko];
            }
            #pragma unroll
            for (int ni = 0; ni < 2; ++ni) {
                b_h[ni] = *(const short8*)&Bsh[wn*32 + ni*16 + fr][ko];
                b_l[ni] = *(const short8*)&Bsl[wn*32 + ni*16 + fr][ko];
            }
            #pragma unroll
            for (int mi = 0; mi < 4; ++mi)
                #pragma unroll
                for (int ni = 0; ni < 2; ++ni) {
                    MF(a_h[mi], b_h[ni], acc[mi][ni]);
                    MF(a_h[mi], b_l[ni], acc[mi][ni]);
                    MF(a_l[mi], b_h[ni], acc[mi][ni]);
                }
        }
        __syncthreads();
        if (t + 1 < t1) {
            WRLDS128();
            __syncthreads();
        }
    }
#undef MF
#undef LOADG128
#undef WRLDS128

    float* Cz = Cp + (size_t)z * M * N;
    #pragma unroll
    for (int mi = 0; mi < 4; ++mi)
        #pragma unroll
        for (int ni = 0; ni < 2; ++ni) {
            const int col = n0 + wn*32 + ni*16 + fr;
            #pragma unroll
            for (int rr = 0; rr < 4; ++rr) {
                const int row = m0 + wm*64 + mi*16 + kh*4 + rr;
                Cz[(size_t)row * N + col] = acc[mi][ni][rr];
            }
        }
}

// ---------------- reduce 8 partials + bias -> xt hi/lo ----------------
__global__ __launch_bounds__(256) void reduce_xt8(const float* __restrict__ Cp,
        const float* __restrict__ bias, u16* __restrict__ xh, u16* __restrict__ xl) {
    int g = blockIdx.x * 256 + threadIdx.x;   // 262144
    int idx = g * 4;
    float4 bv = *(const float4*)(bias + (idx & 1023));
    float v[4] = {bv.x, bv.y, bv.z, bv.w};
    #pragma unroll
    for (int s = 0; s < 8; ++s) {
        float4 a = *(const float4*)(Cp + (size_t)s*1048576 + idx);
        v[0] += a.x; v[1] += a.y; v[2] += a.z; v[3] += a.w;
    }
    ushort4 hh, ll;
    u16* hp = (u16*)&hh; u16* lp = (u16*)&ll;
    #pragma unroll
    for (int j = 0; j < 4; ++j) {
        u16 h = f2bf(v[j]);
        hp[j] = h;
        lp[j] = f2bf(v[j] - bf2f(h));
    }
    *(ushort4*)(xh + idx) = hh;
    *(ushort4*)(xl + idx) = ll;
}

// ---------------- reduce QKV partials (2 x 1024x3072) + bias + per-head normalize ----------------
__global__ __launch_bounds__(256) void reduce_qkv(const float* __restrict__ Cp,
        const float* __restrict__ qbias, const float* __restrict__ kbias,
        const float* __restrict__ vbias,
        float* __restrict__ qo, float* __restrict__ ko, float* __restrict__ vo) {
    int row = blockIdx.x;             // 0..1023
    int t = threadIdx.x;              // 0..255; cols t*4 (within proj), head = t/16
    const float* biases[3] = {qbias, kbias, vbias};
    float* outs[3] = {qo, ko, vo};
    int col = t * 4;
    #pragma unroll
    for (int s = 0; s < 3; ++s) {
        size_t o = (size_t)row*3072 + (size_t)s*1024 + col;
        float4 a = *(const float4*)(Cp + o);
        float4 b = *(const float4*)(Cp + 3145728 + o);
        float4 bv = *(const float4*)(biases[s] + col);
        float v0 = a.x + b.x + bv.x, v1 = a.y + b.y + bv.y;
        float v2 = a.z + b.z + bv.z, v3 = a.w + b.w + bv.w;
        float ss = v0*v0 + v1*v1 + v2*v2 + v3*v3;
        #pragma unroll
        for (int off = 1; off < 16; off <<= 1) ss += __shfl_xor(ss, off);
        float scl = 1.0f / fmaxf(sqrtf(ss), 1e-12f);
        float4 o4 = {v0*scl, v1*scl, v2*scl, v3*scl};
        *(float4*)(outs[s] + (size_t)row*1024 + col) = o4;
    }
}

// ---------------- reduce ns partials, apply rowscale + bias -> fp32 out ----------------
__global__ __launch_bounds__(256) void reduce_out(const float* __restrict__ Cp,
        int ns, const float* __restrict__ rowscale, const float* __restrict__ bias,
        float* __restrict__ out) {
    int g = blockIdx.x * 256 + threadIdx.x;   // 262144
    int idx = g * 4;
    float s0 = 0.f, s1 = 0.f, s2 = 0.f, s3 = 0.f;
    for (int s = 0; s < ns; ++s) {
        float4 a = *(const float4*)(Cp + (size_t)s*1048576 + idx);
        s0 += a.x; s1 += a.y; s2 += a.z; s3 += a.w;
    }
    float4 bv = *(const float4*)(bias + (idx & 1023));
    float rs = rowscale[idx >> 10];
    float4 o = {s0*rs + bv.x, s1*rs + bv.y, s2*rs + bv.z, s3*rs + bv.w};
    *(float4*)(out + idx) = o;
}

// ---------------- attention: per-(head,chunk) locals ----------------
__global__ __launch_bounds__(256) void attn_local(const float* __restrict__ qb,
        const float* __restrict__ kb, const float* __restrict__ vb,
        const float* __restrict__ wgz_w, const float* __restrict__ wgz_b,
        const float* __restrict__ kv_scale, const float* __restrict__ qk_scale,
        float* __restrict__ simG, float* __restrict__ gateG,
        float* __restrict__ Sloc, float* __restrict__ nloc, float* __restrict__ aggL) {
    int c = blockIdx.x, h = blockIdx.y;
    int tid = threadIdx.x;
    __shared__ float q_l[CH][PD], k_l[CH][PD], v_l[CH][PD];
    __shared__ float wg_l[HD][WPD];
    __shared__ float sim_s[CH], gate_s[CH], e_s[CH];

    for (int idx = tid; idx < CH*HD; idx += 256) {
        int i = idx >> 6, d = idx & 63;
        size_t gp = (size_t)(c*CH + i)*DM + h*HD + d;
        q_l[i][d] = qb[gp]; k_l[i][d] = kb[gp]; v_l[i][d] = vb[gp];
        wg_l[i][d] = wgz_w[idx];   // i==p, d==n
    }
    __syncthreads();

    int si = tid >> 2, part = tid & 3;
    float qk_h = qk_scale[h];
    float kv0  = kv_scale[0];

    float sum = 0.f;
    #pragma unroll
    for (int d = 0; d < 16; ++d) sum += q_l[si][part*16+d]*k_l[si][part*16+d];
    sum += __shfl_xor(sum, 1); sum += __shfl_xor(sum, 2);

    float gpart = 0.f;
    for (int pp = 0; pp < 16; ++pp) {
        int p = part*16 + pp;
        float u = 0.f;
        for (int n = 0; n < 64; ++n) u += wg_l[p][n]*k_l[si][n];
        gpart += v_l[si][p]*u;
    }
    gpart += __shfl_xor(gpart, 1); gpart += __shfl_xor(gpart, 2);

    if (part == 0) {
        sim_s[si] = sum * qk_h;
        float raw = kv0*gpart + wgz_b[0];
        gate_s[si] = ((raw > 0.f) ? raw : 0.01f*raw) + EPSF;
    }
    __syncthreads();

    if (tid < CH) {
        simG[h*LSEQ + c*CH + tid]  = sim_s[tid];
        gateG[h*LSEQ + c*CH + tid] = gate_s[tid];
    }

    {
        int p = tid >> 2, nq = tid & 3;
        float acc[16];
        #pragma unroll
        for (int j = 0; j < 16; ++j) acc[j] = 0.f;
        for (int s = 0; s < CH; ++s) {
            float gv = gate_s[s]*v_l[s][p];
            #pragma unroll
            for (int j = 0; j < 16; ++j) acc[j] += gv * k_l[s][nq*16+j];
        }
        size_t so = ((size_t)h*NC + c)*4096 + (size_t)p*64 + nq*16;
        #pragma unroll
        for (int j = 0; j < 16; ++j) Sloc[so+j] = acc[j];
    }

    float m_loc = -INFINITY, s_loc = 0.f, g_sum = 0.f;
    if (tid < 64) {
        float mv = sim_s[tid];
        m_loc = mv;
        #pragma unroll
        for (int off = 32; off >= 1; off >>= 1) m_loc = fmaxf(m_loc, __shfl_xor(m_loc, off));
        float e = expf(mv - m_loc);
        e_s[tid] = e;
        s_loc = e;
        #pragma unroll
        for (int off = 32; off >= 1; off >>= 1) s_loc += __shfl_xor(s_loc, off);
        float gv = gate_s[tid];
        g_sum = gv;
        #pragma unroll
        for (int off = 32; off >= 1; off >>= 1) g_sum += __shfl_xor(g_sum, off);
    }
    __syncthreads();
    if (tid < 64) {
        float nl = 0.f;
        for (int s = 0; s < CH; ++s) nl += e_s[s]*v_l[s][tid];
        nloc[((size_t)h*NC + c)*64 + tid] = nl;
        if (tid == 0) {
            size_t ao = ((size_t)h*NC + c)*4;
            aggL[ao+0] = m_loc; aggL[ao+1] = s_loc; aggL[ao+2] = g_sum;
        }
    }
}

// ---------------- per-(head,chunk) outputs; prefix rebuilt in-block from aggL/nloc/Sloc ----------------
__global__ __launch_bounds__(256) void attn_out(const float* __restrict__ qb,
        const float* __restrict__ kb, const float* __restrict__ vb,
        const float* __restrict__ simG, const float* __restrict__ gateG,
        const float* __restrict__ Sloc, const float* __restrict__ nloc,
        const float* __restrict__ aggL, const float* __restrict__ kv_scale,
        float* __restrict__ Y, u16* __restrict__ yh, u16* __restrict__ yl) {
    int c = blockIdx.x, h = blockIdx.y;
    int tid = threadIdx.x;
    __shared__ float q_l[CH][PD], k_l[CH][PD], v_l[CH][PD], sp_l[HD][PD];
    __shared__ float a_l[CH][PD], m_l[CH][PD];
    __shared__ float sim_s[CH], gate_s[CH], mc_s[CH], ep_s[CH], gc_s[CH],
                     sc_s[CH], w_s2[CH], qs_s[CH], np_l[HD];
    __shared__ float agg_s[NC][3];
    size_t hb = (size_t)h*NC;

    for (int idx = tid; idx < CH*HD; idx += 256) {
        int i = idx >> 6, d = idx & 63;
        size_t gp = (size_t)(c*CH + i)*DM + h*HD + d;
        q_l[i][d] = qb[gp]; k_l[i][d] = kb[gp]; v_l[i][d] = vb[gp];
    }
    {   // Spre = sum_{cc<c} Sloc[h][cc]  (parallel, L2-hot)
        float4 s[4] = {{0,0,0,0},{0,0,0,0},{0,0,0,0},{0,0,0,0}};
        for (int cc = 0; cc < c; ++cc) {
            const float* src = Sloc + (hb + cc)*4096 + (size_t)tid*16;
            #pragma unroll
            for (int j = 0; j < 4; ++j) {
                float4 a = *(const float4*)(src + j*4);
                s[j].x += a.x; s[j].y += a.y; s[j].z += a.z; s[j].w += a.w;
            }
        }
        int p = tid >> 2, nq = (tid & 3) * 16;
        #pragma unroll
        for (int j = 0; j < 4; ++j)
            *(float4*)&sp_l[p][nq + j*4] = s[j];
    }
    if (tid < CH) {
        sim_s[tid]  = simG[h*LSEQ + c*CH + tid];
        gate_s[tid] = gateG[h*LSEQ + c*CH + tid];
    }
    if (tid < NC*3) {
        int cc = tid / 3, f = tid - cc*3;
        agg_s[cc][f] = aggL[(hb + cc)*4 + f];
    }
    __syncthreads();

    // prefix scalars (redundant per-thread; c<=15 iterations)
    float m_p = -INFINITY, s_p = 0.f, g_p = 0.f;
    for (int cc = 0; cc < c; ++cc) m_p = fmaxf(m_p, agg_s[cc][0]);
    for (int cc = 0; cc < c; ++cc) {
        s_p += agg_s[cc][1] * expf(agg_s[cc][0] - m_p);
        g_p += agg_s[cc][2];
    }
    float kv0 = kv_scale[0];

    if (tid < HD) {   // npre
        float nv = 0.f;
        for (int cc = 0; cc < c; ++cc)
            nv += expf(agg_s[cc][0] - m_p) * nloc[(hb + cc)*64 + tid];
        np_l[tid] = nv;
    }
    if (tid < CH) {   // per-row within-chunk prefixes
        int i = tid;
        float mloc = -INFINITY, gcum = 0.f;
        for (int s = 0; s <= i; ++s) { mloc = fmaxf(mloc, sim_s[s]); gcum += gate_s[s]; }
        float mc = fmaxf(m_p, mloc);
        mc_s[i] = mc;
        ep_s[i] = expf(m_p - mc);
        gc_s[i] = g_p + gcum;
        float qs = 0.f;
        for (int d = 0; d < 64; ++d) qs += q_l[i][d];
        qs_s[i] = qs;
    }
    __syncthreads();

    {   // M[i][s] and gated-masked A[i][s]
        int i = tid >> 2, sq = tid & 3;
        float mci = mc_s[i];
        #pragma unroll
        for (int jj = 0; jj < 16; ++jj) {
            int s = sq*16 + jj;
            float Mv = 0.f, Av = 0.f;
            if (s <= i) {
                Mv = expf(sim_s[s] - mci);
                float dot = 0.f;
                #pragma unroll
                for (int dq = 0; dq < 16; ++dq) {
                    float4 q4 = *(const float4*)&q_l[i][dq*4];
                    float4 v4 = *(const float4*)&v_l[s][dq*4];
                    dot += q4.x*v4.x + q4.y*v4.y + q4.z*v4.z + q4.w*v4.w;
                }
                Av = gate_s[s]*dot;
            }
            m_l[i][s] = Mv;
            a_l[i][s] = Av;
        }
    }
    __syncthreads();

    if (tid < CH) {   // row sums of M -> s_c, w
        int i = tid;
        float rs = 0.f;
        for (int s = 0; s < CH; ++s) rs += m_l[i][s];
        float sc = ep_s[i]*s_p + rs;
        sc_s[i] = sc;
        w_s2[i] = expf(sim_s[i] - mc_s[i]) / (sc + EPSF);
    }
    __syncthreads();

    {   // outputs
        int i = tid >> 2, nq = tid & 3;
        float yb[16], ncv[16];
        #pragma unroll
        for (int j = 0; j < 16; ++j) { yb[j] = 0.f; ncv[j] = 0.f; }
        for (int p = 0; p < 64; ++p) {
            float qv = q_l[i][p];
            float av = a_l[i][p];
            float mv = m_l[i][p];
            #pragma unroll
            for (int jq = 0; jq < 4; ++jq) {
                float4 sp4 = *(const float4*)&sp_l[p][nq*16 + jq*4];
                float4 k4  = *(const float4*)&k_l[p][nq*16 + jq*4];
                float4 v4  = *(const float4*)&v_l[p][nq*16 + jq*4];
                yb[jq*4+0] += qv*sp4.x + av*k4.x;  ncv[jq*4+0] += mv*v4.x;
                yb[jq*4+1] += qv*sp4.y + av*k4.y;  ncv[jq*4+1] += mv*v4.y;
                yb[jq*4+2] += qv*sp4.z + av*k4.z;  ncv[jq*4+2] += mv*v4.z;
                yb[jq*4+3] += qv*sp4.w + av*k4.w;  ncv[jq*4+3] += mv*v4.w;
            }
        }
        float gsc   = kv0 / (gc_s[i] + EPSF);
        float invsc = 1.0f / (sc_s[i] + EPSF);
        float ep = ep_s[i], wv = w_s2[i], qs = qs_s[i];
        size_t yo = (size_t)(c*CH + i)*DM + h*HD + nq*16;
        #pragma unroll
        for (int j = 0; j < 16; ++j) {
            float Ybase = yb[j] * gsc;
            float lin   = (ep*np_l[nq*16+j] + ncv[j]) * invsc;
            float val = Ybase + (qs*lin - Ybase)*wv;
            Y[yo + j] = val;
            u16 hh = f2bf(val);
            yh[yo + j] = hh;
            yl[yo + j] = f2bf(val - bf2f(hh));
        }
    }
}

// ---------------- row 1/max(||.||,1e-12) over D=1024 ----------------
__global__ __launch_bounds__(256) void rownorm(const float* __restrict__ Y,
        float* __restrict__ rn) {
    int row = blockIdx.x;
    int tid = threadIdx.x;
    float4 v = *(const float4*)&Y[(size_t)row*DM + tid*4];
    float ss = v.x*v.x + v.y*v.y + v.z*v.z + v.w*v.w;
    #pragma unroll
    for (int off = 32; off >= 1; off >>= 1) ss += __shfl_xor(ss, off);
    __shared__ float wsum[4];
    if ((tid & 63) == 0) wsum[tid >> 6] = ss;
    __syncthreads();
    if (tid == 0) {
        float tot = wsum[0] + wsum[1] + wsum[2] + wsum[3];
        rn[row] = 1.0f / fmaxf(sqrtf(tot), 1e-12f);
    }
}

extern "C" void kernel_launch(void* const* d_in, const int* in_sizes, int n_in,
                              void* d_out, int out_size, void* d_ws, size_t ws_size,
                              hipStream_t stream) {
    const float* x      = (const float*)d_in[0];
    const float* conv_w = (const float*)d_in[1];
    const float* conv_b = (const float*)d_in[2];
    const float* mphi_w = (const float*)d_in[3];
    const float* mphi_b = (const float*)d_in[4];
    const float* wq_w   = (const float*)d_in[5];
    const float* wq_b   = (const float*)d_in[6];
    const float* wk_w   = (const float*)d_in[7];
    const float* wk_b   = (const float*)d_in[8];
    const float* wv_w   = (const float*)d_in[9];
    const float* wv_b   = (const float*)d_in[10];
    const float* wo_w   = (const float*)d_in[11];
    const float* wo_b   = (const float*)d_in[12];
    const float* wgz_w  = (const float*)d_in[13];
    const float* wgz_b  = (const float*)d_in[14];
    const float* kv_sc  = (const float*)d_in[15];
    const float* qk_sc  = (const float*)d_in[16];
    float* out = (float*)d_out;

    // ---- workspace layout (1 MB units in comments), peak ~100 MB ----
    char* p = (char*)d_ws;
    u16*  xr_h    = (u16*)p;                      // [0,16)
    u16*  xr_l    = (u16*)(p + 16777216);         // [16,32)
    u16*  mphiT_h = (u16*)(p + 33554432);         // [32,48)
    u16*  mphiT_l = (u16*)(p + 50331648);         // [48,64)
    float* g1Part = (float*)(p + 67108864);       // [64,96)  8 x 4MB
    u16*  xt_h    = (u16*)(p + 100663296);        // [96,98)
    u16*  xt_l    = (u16*)(p + 102760448);        // [98,100)
    // after GEMM1 (xr/mphiT dead):
    u16*  wqkvT_h = (u16*)p;                      // [0,6)   wq|wk|wv rows stacked
    u16*  wqkvT_l = (u16*)(p + 6291456);          // [6,12)
    u16*  woT_h   = (u16*)(p + 12582912);         // [12,14)
    u16*  woT_l   = (u16*)(p + 14680064);         // [14,16)
    float* qkvPart= (float*)(p + 16777216);       // [16,40)  2 x 12MB
    float* qb     = (float*)(p + 67108864);       // [64,68)  (g1Part dead after reduce_xt8)
    float* kb     = (float*)(p + 71303168);       // [68,72)
    float* vb     = (float*)(p + 75497472);       // [72,76)
    float* Sloc   = (float*)(p + 79691776);       // [76,80)
    float* Ybuf   = (float*)(p + 41943040);       // [40,44)  (qkvPart dead after reduce_qkv)
    u16*  y_h     = (u16*)(p + 46137344);         // [44,46)
    u16*  y_l     = (u16*)(p + 48234496);         // [46,48)
    float* woPart = (float*)(p + 50331648);       // [48,64)  4 x 4MB (after attn)
    char* q2 = p + 88080384;                      // [84,...) small buffers
    float* simG  = (float*)q2; q2 += 65536;
    float* gateG = (float*)q2; q2 += 65536;
    float* nlocp = (float*)q2; q2 += 65536;
    float* aggL  = (float*)q2; q2 += 4096;
    float* rn    = (float*)q2; q2 += 4096;

    conv_reorder<<<4096, 256, 0, stream>>>(x, conv_w, conv_b, xr_h, xr_l);
    wconv_t<<<dim3(32, 256), 256, 0, stream>>>(mphi_w, mphiT_h, mphiT_l, 8192, 1024);

    // GEMM1: xt = xr @ mphi (split-K=8, fp32 partials, then reduce + bias + bf16 split)
    gemm_bf16x3_128<<<dim3(8, 8, 8), 512, 0, stream>>>(xr_h, xr_l, mphiT_h, mphiT_l,
            g1Part, 1024, 1024, 8192);
    reduce_xt8<<<1024, 256, 0, stream>>>(g1Part, mphi_b, xt_h, xt_l);

    // weights for QKV (stacked N=3072) and WO in one dispatch; xr/mphiT regions dead
    wconv_t4<<<dim3(32, 32, 4), 256, 0, stream>>>(wq_w, wk_w, wv_w, wo_w,
            wqkvT_h, wqkvT_l, woT_h, woT_l);

    // QKV fused: (1024 x 3072) = xt @ [wq|wk|wv], split-K=2; reduce adds bias + per-head norm
    gemm_bf16x3_128<<<dim3(24, 8, 2), 512, 0, stream>>>(xt_h, xt_l, wqkvT_h, wqkvT_l,
            qkvPart, 1024, 3072, 1024);
    reduce_qkv<<<1024, 256, 0, stream>>>(qkvPart, wq_b, wk_b, wv_b, qb, kb, vb);

    attn_local<<<dim3(NC, NH), 256, 0, stream>>>(qb, kb, vb, wgz_w, wgz_b, kv_sc, qk_sc,
                                                 simG, gateG, Sloc, nlocp, aggL);
    attn_out<<<dim3(NC, NH), 256, 0, stream>>>(qb, kb, vb, simG, gateG, Sloc, nlocp, aggL,
                                               kv_sc, Ybuf, y_h, y_l);
    rownorm<<<1024, 256, 0, stream>>>(Ybuf, rn);

    // WO: out = normalize(Y) @ wo + b (split-K=4; rowscale+bias in reduce)
    gemm_bf16x3_128<<<dim3(8, 8, 4), 512, 0, stream>>>(y_h, y_l, woT_h, woT_l,
            woPart, 1024, 1024, 1024);
    reduce_out<<<1024, 256, 0, stream>>>(woPart, 4, rn, wo_b, out);
}

// Round 7
// 286.546 us; speedup vs baseline: 1.2776x; 1.1384x over previous
//
#include <hip/hip_runtime.h>
#include <math.h>

// Problem constants (B=1)
#define LSEQ 1024
#define DM   1024
#define NH   16
#define HD   64
#define KEXP 8
#define NC   16   // chunks
#define CH   64   // chunk length
#define EPSF 1e-5f
#define PD   68   // LDS row pad (words) for attn kernels
#define WPD  65

typedef unsigned short u16;
typedef unsigned int   u32;
typedef __attribute__((ext_vector_type(8))) short short8;   // 8 bf16 (4 VGPRs)
typedef __attribute__((ext_vector_type(4))) float f32x4;

__device__ __forceinline__ u16 f2bf(float f) {
    u32 u = __float_as_uint(f);
    return (u16)((u + 0x7fffu + ((u >> 16) & 1u)) >> 16);   // RNE
}
__device__ __forceinline__ float bf2f(u16 h) {
    return __uint_as_float(((u32)h) << 16);
}

// ---------------- x -> zero-padded (2 rows) bf16 hi/lo split; also zeroes beff ----------------
__global__ __launch_bounds__(256) void xsplit(const float* __restrict__ x,
        u16* __restrict__ xph, u16* __restrict__ xpl, float* __restrict__ beff) {
    int g = blockIdx.x * 256 + threadIdx.x;   // [0, 1026*1024)
    int row = g >> 10, d = g & 1023;
    float val = (row < 2) ? 0.f : x[(size_t)(row - 2) * 1024 + d];
    u16 h = f2bf(val);
    xph[g] = h;
    xpl[g] = f2bf(val - bf2f(h));
    if (g < 1024) beff[g] = 0.f;
}

// ---------------- W~_j[d,n] = sum_kk cw[d*8+kk, j] * mphi[kk*1024+d, n]  (+ conv-bias fold) ----
// writes Bt layout [n][j*1024+d] hi/lo; atomicAdds C[n] = sum cb*mphi into beff.
__global__ __launch_bounds__(256) void wtilde(const float* __restrict__ mphi,
        const float* __restrict__ cw, const float* __restrict__ cb,
        u16* __restrict__ wth, u16* __restrict__ wtl, float* __restrict__ beff) {
    __shared__ float wl[3][32][33];
    __shared__ float cbp[8][33];
    int n0 = blockIdx.x * 32, d0 = blockIdx.y * 32;
    int tx = threadIdx.x & 31, ty = threadIdx.x >> 5;
    float cbacc = 0.f;
    #pragma unroll
    for (int k2 = 0; k2 < 4; ++k2) {
        int d = d0 + ty + 8*k2;
        int n = n0 + tx;
        float s0 = 0.f, s1 = 0.f, s2 = 0.f, cbs = 0.f;
        #pragma unroll
        for (int kk = 0; kk < 8; ++kk) {
            float mv = mphi[((size_t)(kk*1024 + d))*1024 + n];
            const float* cwp = cw + (size_t)(d*8 + kk)*3;
            s0 += cwp[0]*mv; s1 += cwp[1]*mv; s2 += cwp[2]*mv;
            cbs += cb[d*8 + kk]*mv;
        }
        wl[0][ty+8*k2][tx] = s0;
        wl[1][ty+8*k2][tx] = s1;
        wl[2][ty+8*k2][tx] = s2;
        cbacc += cbs;
    }
    cbp[ty][tx] = cbacc;
    __syncthreads();
    #pragma unroll
    for (int k2 = 0; k2 < 4; ++k2) {
        int nn = n0 + ty + 8*k2;
        #pragma unroll
        for (int j = 0; j < 3; ++j) {
            float v = wl[j][tx][ty+8*k2];
            u16 h = f2bf(v);
            size_t o = (size_t)nn*3072 + j*1024 + d0 + tx;
            wth[o] = h;
            wtl[o] = f2bf(v - bf2f(h));
        }
    }
    if (ty == 0) {
        float s = 0.f;
        #pragma unroll
        for (int r = 0; r < 8; ++r) s += cbp[r][tx];
        atomicAdd(beff + n0 + tx, s);
    }
}

// ---------------- merged 4-weight transpose (1024x1024 each), z picks source/dest ----------------
__global__ __launch_bounds__(256) void wconv_t4(const float* __restrict__ W0,
        const float* __restrict__ W1, const float* __restrict__ W2,
        const float* __restrict__ W3,
        u16* __restrict__ Tqkv_h, u16* __restrict__ Tqkv_l,
        u16* __restrict__ To_h, u16* __restrict__ To_l) {
    __shared__ float t[32][33];
    int z = blockIdx.z;
    const float* W = (z == 0) ? W0 : (z == 1) ? W1 : (z == 2) ? W2 : W3;
    u16* Th = (z < 3) ? Tqkv_h + (size_t)z*1048576 : To_h;
    u16* Tl = (z < 3) ? Tqkv_l + (size_t)z*1048576 : To_l;
    int c0 = blockIdx.x*32, r0 = blockIdx.y*32;
    int tx = threadIdx.x & 31, ty = threadIdx.x >> 5;
    #pragma unroll
    for (int k2 = 0; k2 < 4; ++k2)
        t[ty+8*k2][tx] = W[(size_t)(r0+ty+8*k2)*1024 + c0+tx];
    __syncthreads();
    #pragma unroll
    for (int k2 = 0; k2 < 4; ++k2) {
        float v = t[tx][ty+8*k2];
        u16 h = f2bf(v);
        size_t o = (size_t)(c0+ty+8*k2)*1024 + r0+tx;
        Th[o] = h;
        Tl[o] = f2bf(v - bf2f(h));
    }
}

#define MF(a_,b_,c_) c_ = __builtin_amdgcn_mfma_f32_16x16x32_bf16(a_, b_, c_, 0, 0, 0)

// ---------------- conv-fused GEMM1: xt_part = [x(t-2)|x(t-1)|x(t)] @ W~  (K=3072) ----------------
// grid (8,8,8): XCD rectangle map; A = padded x rows (t + j), j = K-block.
__global__ __launch_bounds__(512, 4) void gemm_conv3(
        const u16* __restrict__ xph, const u16* __restrict__ xpl,
        const u16* __restrict__ Bth, const u16* __restrict__ Btl,
        float* __restrict__ Cp) {
    __shared__ u16 Ash[128][72];
    __shared__ u16 Asl[128][72];
    __shared__ u16 Bsh[128][72];
    __shared__ u16 Bsl[128][72];

    const int tid = threadIdx.x;
    const int z = blockIdx.z, Z = gridDim.z;
    const int mpan = ((blockIdx.x >> 1) << 1) + (blockIdx.y >> 2);
    const int npan = ((blockIdx.x & 1) << 2) + (blockIdx.y & 3);
    const int m0 = mpan * 128, n0 = npan * 128;
    const int lane = tid & 63, w = tid >> 6;
    const int wm = w >> 2, wn = w & 3;
    const int fr = lane & 15, kh = lane >> 4;

    const int r0 = tid >> 3;
    const int sl = (tid + (tid >> 3)) & 7;
    const int sc = sl * 8;
    const size_t bO0 = (size_t)(n0 + r0)      * 3072 + sc;
    const size_t bO1 = (size_t)(n0 + r0 + 64) * 3072 + sc;

    const int ktiles = 48;
    const int t0 = (ktiles * z) / Z, t1 = (ktiles * (z + 1)) / Z;

    uint4 ra0h, ra0l, ra1h, ra1l, rb0h, rb0l, rb1h, rb1l;
    f32x4 acc[4][2];
    #pragma unroll
    for (int mi = 0; mi < 4; ++mi)
        #pragma unroll
        for (int ni = 0; ni < 2; ++ni) acc[mi][ni] = (f32x4){0,0,0,0};

#define LOADC3(t_) { int j_ = (t_) >> 4; int doff_ = ((t_) & 15) * 64;   \
        size_t ao_ = ((size_t)(m0 + r0 + j_) << 10) + doff_ + sc;        \
        ra0h = *(const uint4*)(xph + ao_);                               \
        ra0l = *(const uint4*)(xpl + ao_);                               \
        ra1h = *(const uint4*)(xph + ao_ + 65536);                       \
        ra1l = *(const uint4*)(xpl + ao_ + 65536);                       \
        size_t bo_ = (size_t)(t_) * 64;                                  \
        rb0h = *(const uint4*)(Bth + bO0 + bo_);                         \
        rb0l = *(const uint4*)(Btl + bO0 + bo_);                         \
        rb1h = *(const uint4*)(Bth + bO1 + bo_);                         \
        rb1l = *(const uint4*)(Btl + bO1 + bo_); }
#define WRLDS128() {                                                     \
        *(uint4*)&Ash[r0   ][sc] = ra0h; *(uint4*)&Asl[r0   ][sc] = ra0l; \
        *(uint4*)&Ash[r0+64][sc] = ra1h; *(uint4*)&Asl[r0+64][sc] = ra1l; \
        *(uint4*)&Bsh[r0   ][sc] = rb0h; *(uint4*)&Bsl[r0   ][sc] = rb0l; \
        *(uint4*)&Bsh[r0+64][sc] = rb1h; *(uint4*)&Bsl[r0+64][sc] = rb1l; }

    LOADC3(t0);
    WRLDS128();
    __syncthreads();

    for (int t = t0; t < t1; ++t) {
        if (t + 1 < t1) LOADC3(t + 1);
        #pragma unroll
        for (int ks = 0; ks < 2; ++ks) {
            const int ko = ks*32 + kh*8;
            short8 a_h[4], a_l[4], b_h[2], b_l[2];
            #pragma unroll
            for (int mi = 0; mi < 4; ++mi) {
                a_h[mi] = *(const short8*)&Ash[wm*64 + mi*16 + fr][ko];
                a_l[mi] = *(const short8*)&Asl[wm*64 + mi*16 + fr][ko];
            }
            #pragma unroll
            for (int ni = 0; ni < 2; ++ni) {
                b_h[ni] = *(const short8*)&Bsh[wn*32 + ni*16 + fr][ko];
                b_l[ni] = *(const short8*)&Bsl[wn*32 + ni*16 + fr][ko];
            }
            #pragma unroll
            for (int mi = 0; mi < 4; ++mi)
                #pragma unroll
                for (int ni = 0; ni < 2; ++ni) {
                    MF(a_h[mi], b_h[ni], acc[mi][ni]);
                    MF(a_h[mi], b_l[ni], acc[mi][ni]);
                    MF(a_l[mi], b_h[ni], acc[mi][ni]);
                }
        }
        __syncthreads();
        if (t + 1 < t1) {
            WRLDS128();
            __syncthreads();
        }
    }
#undef LOADC3
#undef WRLDS128

    float* Cz = Cp + (size_t)z * 1048576;
    #pragma unroll
    for (int mi = 0; mi < 4; ++mi)
        #pragma unroll
        for (int ni = 0; ni < 2; ++ni) {
            const int col = n0 + wn*32 + ni*16 + fr;
            #pragma unroll
            for (int rr = 0; rr < 4; ++rr) {
                const int row = m0 + wm*64 + mi*16 + kh*4 + rr;
                Cz[(size_t)row * 1024 + col] = acc[mi][ni][rr];
            }
        }
}

// ---------------- generic 128x128 split-K MFMA GEMM (bf16 hi/lo ×3), fp32 partials ----------------
__global__ __launch_bounds__(512, 4) void gemm_bf16x3_128(
        const u16* __restrict__ Ah, const u16* __restrict__ Al,
        const u16* __restrict__ Bth, const u16* __restrict__ Btl,
        float* __restrict__ Cp, int M, int N, int K) {
    __shared__ u16 Ash[128][72];
    __shared__ u16 Asl[128][72];
    __shared__ u16 Bsh[128][72];
    __shared__ u16 Bsl[128][72];

    const int tid = threadIdx.x;
    const int z = blockIdx.z, Z = gridDim.z;
    int mpan, npan;
    if (gridDim.x == 8 && gridDim.y == 8) {
        mpan = ((blockIdx.x >> 1) << 1) + (blockIdx.y >> 2);
        npan = ((blockIdx.x & 1) << 2) + (blockIdx.y & 3);
    } else {
        const int id = blockIdx.y * gridDim.x + blockIdx.x;
        mpan = id % gridDim.y;
        npan = id / gridDim.y;
    }
    const int m0 = mpan * 128, n0 = npan * 128;
    const int lane = tid & 63, w = tid >> 6;
    const int wm = w >> 2, wn = w & 3;
    const int fr = lane & 15, kh = lane >> 4;

    const int r0 = tid >> 3;
    const int sl = (tid + (tid >> 3)) & 7;
    const int sc = sl * 8;
    const size_t aO0 = (size_t)(m0 + r0)      * K + sc;
    const size_t aO1 = (size_t)(m0 + r0 + 64) * K + sc;
    const size_t bO0 = (size_t)(n0 + r0)      * K + sc;
    const size_t bO1 = (size_t)(n0 + r0 + 64) * K + sc;

    const int ktiles = K >> 6;
    const int t0 = (ktiles * z) / Z, t1 = (ktiles * (z + 1)) / Z;

    uint4 ra0h, ra0l, ra1h, ra1l, rb0h, rb0l, rb1h, rb1l;
    f32x4 acc[4][2];
    #pragma unroll
    for (int mi = 0; mi < 4; ++mi)
        #pragma unroll
        for (int ni = 0; ni < 2; ++ni) acc[mi][ni] = (f32x4){0,0,0,0};

#define LOADG128(t_) { size_t ko_ = (size_t)(t_) * 64;                  \
        ra0h = *(const uint4*)(Ah  + aO0 + ko_);                        \
        ra0l = *(const uint4*)(Al  + aO0 + ko_);                        \
        ra1h = *(const uint4*)(Ah  + aO1 + ko_);                        \
        ra1l = *(const uint4*)(Al  + aO1 + ko_);                        \
        rb0h = *(const uint4*)(Bth + bO0 + ko_);                        \
        rb0l = *(const uint4*)(Btl + bO0 + ko_);                        \
        rb1h = *(const uint4*)(Bth + bO1 + ko_);                        \
        rb1l = *(const uint4*)(Btl + bO1 + ko_); }
#define WRLDS128() {                                                    \
        *(uint4*)&Ash[r0   ][sc] = ra0h; *(uint4*)&Asl[r0   ][sc] = ra0l; \
        *(uint4*)&Ash[r0+64][sc] = ra1h; *(uint4*)&Asl[r0+64][sc] = ra1l; \
        *(uint4*)&Bsh[r0   ][sc] = rb0h; *(uint4*)&Bsl[r0   ][sc] = rb0l; \
        *(uint4*)&Bsh[r0+64][sc] = rb1h; *(uint4*)&Bsl[r0+64][sc] = rb1l; }

    LOADG128(t0);
    WRLDS128();
    __syncthreads();

    for (int t = t0; t < t1; ++t) {
        if (t + 1 < t1) LOADG128(t + 1);
        #pragma unroll
        for (int ks = 0; ks < 2; ++ks) {
            const int ko = ks*32 + kh*8;
            short8 a_h[4], a_l[4], b_h[2], b_l[2];
            #pragma unroll
            for (int mi = 0; mi < 4; ++mi) {
                a_h[mi] = *(const short8*)&Ash[wm*64 + mi*16 + fr][ko];
                a_l[mi] = *(const short8*)&Asl[wm*64 + mi*16 + fr][ko];
            }
            #pragma unroll
            for (int ni = 0; ni < 2; ++ni) {
                b_h[ni] = *(const short8*)&Bsh[wn*32 + ni*16 + fr][ko];
                b_l[ni] = *(const short8*)&Bsl[wn*32 + ni*16 + fr][ko];
            }
            #pragma unroll
            for (int mi = 0; mi < 4; ++mi)
                #pragma unroll
                for (int ni = 0; ni < 2; ++ni) {
                    MF(a_h[mi], b_h[ni], acc[mi][ni]);
                    MF(a_h[mi], b_l[ni], acc[mi][ni]);
                    MF(a_l[mi], b_h[ni], acc[mi][ni]);
                }
        }
        __syncthreads();
        if (t + 1 < t1) {
            WRLDS128();
            __syncthreads();
        }
    }
#undef LOADG128
#undef WRLDS128

    float* Cz = Cp + (size_t)z * M * N;
    #pragma unroll
    for (int mi = 0; mi < 4; ++mi)
        #pragma unroll
        for (int ni = 0; ni < 2; ++ni) {
            const int col = n0 + wn*32 + ni*16 + fr;
            #pragma unroll
            for (int rr = 0; rr < 4; ++rr) {
                const int row = m0 + wm*64 + mi*16 + kh*4 + rr;
                Cz[(size_t)row * N + col] = acc[mi][ni][rr];
            }
        }
}

// ---------------- reduce 8 partials + (mphi_b + beff) -> xt hi/lo ----------------
__global__ __launch_bounds__(256) void reduce_xt8(const float* __restrict__ Cp,
        const float* __restrict__ bias, const float* __restrict__ beff,
        u16* __restrict__ xh, u16* __restrict__ xl) {
    int g = blockIdx.x * 256 + threadIdx.x;   // 262144
    int idx = g * 4;
    float4 bv = *(const float4*)(bias + (idx & 1023));
    float4 be = *(const float4*)(beff + (idx & 1023));
    float v[4] = {bv.x + be.x, bv.y + be.y, bv.z + be.z, bv.w + be.w};
    #pragma unroll
    for (int s = 0; s < 8; ++s) {
        float4 a = *(const float4*)(Cp + (size_t)s*1048576 + idx);
        v[0] += a.x; v[1] += a.y; v[2] += a.z; v[3] += a.w;
    }
    ushort4 hh, ll;
    u16* hp = (u16*)&hh; u16* lp = (u16*)&ll;
    #pragma unroll
    for (int j = 0; j < 4; ++j) {
        u16 h = f2bf(v[j]);
        hp[j] = h;
        lp[j] = f2bf(v[j] - bf2f(h));
    }
    *(ushort4*)(xh + idx) = hh;
    *(ushort4*)(xl + idx) = ll;
}

// ---------------- reduce QKV partials (2 x 1024x3072) + bias + per-head normalize ----------------
__global__ __launch_bounds__(256) void reduce_qkv(const float* __restrict__ Cp,
        const float* __restrict__ qbias, const float* __restrict__ kbias,
        const float* __restrict__ vbias,
        float* __restrict__ qo, float* __restrict__ ko, float* __restrict__ vo) {
    int row = blockIdx.x;
    int t = threadIdx.x;
    const float* biases[3] = {qbias, kbias, vbias};
    float* outs[3] = {qo, ko, vo};
    int col = t * 4;
    #pragma unroll
    for (int s = 0; s < 3; ++s) {
        size_t o = (size_t)row*3072 + (size_t)s*1024 + col;
        float4 a = *(const float4*)(Cp + o);
        float4 b = *(const float4*)(Cp + 3145728 + o);
        float4 bv = *(const float4*)(biases[s] + col);
        float v0 = a.x + b.x + bv.x, v1 = a.y + b.y + bv.y;
        float v2 = a.z + b.z + bv.z, v3 = a.w + b.w + bv.w;
        float ss = v0*v0 + v1*v1 + v2*v2 + v3*v3;
        #pragma unroll
        for (int off = 1; off < 16; off <<= 1) ss += __shfl_xor(ss, off);
        float scl = 1.0f / fmaxf(sqrtf(ss), 1e-12f);
        float4 o4 = {v0*scl, v1*scl, v2*scl, v3*scl};
        *(float4*)(outs[s] + (size_t)row*1024 + col) = o4;
    }
}

// ---------------- reduce ns partials, apply rowscale + bias -> fp32 out ----------------
__global__ __launch_bounds__(256) void reduce_out(const float* __restrict__ Cp,
        int ns, const float* __restrict__ rowscale, const float* __restrict__ bias,
        float* __restrict__ out) {
    int g = blockIdx.x * 256 + threadIdx.x;
    int idx = g * 4;
    float s0 = 0.f, s1 = 0.f, s2 = 0.f, s3 = 0.f;
    for (int s = 0; s < ns; ++s) {
        float4 a = *(const float4*)(Cp + (size_t)s*1048576 + idx);
        s0 += a.x; s1 += a.y; s2 += a.z; s3 += a.w;
    }
    float4 bv = *(const float4*)(bias + (idx & 1023));
    float rs = rowscale[idx >> 10];
    float4 o = {s0*rs + bv.x, s1*rs + bv.y, s2*rs + bv.z, s3*rs + bv.w};
    *(float4*)(out + idx) = o;
}

// ---------------- attention: per-(head,chunk) locals ----------------
__global__ __launch_bounds__(256) void attn_local(const float* __restrict__ qb,
        const float* __restrict__ kb, const float* __restrict__ vb,
        const float* __restrict__ wgz_w, const float* __restrict__ wgz_b,
        const float* __restrict__ kv_scale, const float* __restrict__ qk_scale,
        float* __restrict__ simG, float* __restrict__ gateG,
        float* __restrict__ Sloc, float* __restrict__ nloc, float* __restrict__ aggL) {
    int c = blockIdx.x, h = blockIdx.y;
    int tid = threadIdx.x;
    __shared__ float q_l[CH][PD], k_l[CH][PD], v_l[CH][PD];
    __shared__ float wg_l[HD][WPD];
    __shared__ float sim_s[CH], gate_s[CH], e_s[CH];

    for (int idx = tid; idx < CH*HD; idx += 256) {
        int i = idx >> 6, d = idx & 63;
        size_t gp = (size_t)(c*CH + i)*DM + h*HD + d;
        q_l[i][d] = qb[gp]; k_l[i][d] = kb[gp]; v_l[i][d] = vb[gp];
        wg_l[i][d] = wgz_w[idx];
    }
    __syncthreads();

    int si = tid >> 2, part = tid & 3;
    float qk_h = qk_scale[h];
    float kv0  = kv_scale[0];

    float sum = 0.f;
    #pragma unroll
    for (int d = 0; d < 16; ++d) sum += q_l[si][part*16+d]*k_l[si][part*16+d];
    sum += __shfl_xor(sum, 1); sum += __shfl_xor(sum, 2);

    float gpart = 0.f;
    for (int pp = 0; pp < 16; ++pp) {
        int p = part*16 + pp;
        float u = 0.f;
        for (int n = 0; n < 64; ++n) u += wg_l[p][n]*k_l[si][n];
        gpart += v_l[si][p]*u;
    }
    gpart += __shfl_xor(gpart, 1); gpart += __shfl_xor(gpart, 2);

    if (part == 0) {
        sim_s[si] = sum * qk_h;
        float raw = kv0*gpart + wgz_b[0];
        gate_s[si] = ((raw > 0.f) ? raw : 0.01f*raw) + EPSF;
    }
    __syncthreads();

    if (tid < CH) {
        simG[h*LSEQ + c*CH + tid]  = sim_s[tid];
        gateG[h*LSEQ + c*CH + tid] = gate_s[tid];
    }

    {
        int p = tid >> 2, nq = tid & 3;
        float acc[16];
        #pragma unroll
        for (int j = 0; j < 16; ++j) acc[j] = 0.f;
        for (int s = 0; s < CH; ++s) {
            float gv = gate_s[s]*v_l[s][p];
            #pragma unroll
            for (int j = 0; j < 16; ++j) acc[j] += gv * k_l[s][nq*16+j];
        }
        size_t so = ((size_t)h*NC + c)*4096 + (size_t)p*64 + nq*16;
        #pragma unroll
        for (int j = 0; j < 16; ++j) Sloc[so+j] = acc[j];
    }

    float m_loc = -INFINITY, s_loc = 0.f, g_sum = 0.f;
    if (tid < 64) {
        float mv = sim_s[tid];
        m_loc = mv;
        #pragma unroll
        for (int off = 32; off >= 1; off >>= 1) m_loc = fmaxf(m_loc, __shfl_xor(m_loc, off));
        float e = expf(mv - m_loc);
        e_s[tid] = e;
        s_loc = e;
        #pragma unroll
        for (int off = 32; off >= 1; off >>= 1) s_loc += __shfl_xor(s_loc, off);
        float gv = gate_s[tid];
        g_sum = gv;
        #pragma unroll
        for (int off = 32; off >= 1; off >>= 1) g_sum += __shfl_xor(g_sum, off);
    }
    __syncthreads();
    if (tid < 64) {
        float nl = 0.f;
        for (int s = 0; s < CH; ++s) nl += e_s[s]*v_l[s][tid];
        nloc[((size_t)h*NC + c)*64 + tid] = nl;
        if (tid == 0) {
            size_t ao = ((size_t)h*NC + c)*4;
            aggL[ao+0] = m_loc; aggL[ao+1] = s_loc; aggL[ao+2] = g_sum;
        }
    }
}

// ---------------- per-(head,chunk) outputs; prefix rebuilt in-block from aggL/nloc/Sloc ----------------
__global__ __launch_bounds__(256) void attn_out(const float* __restrict__ qb,
        const float* __restrict__ kb, const float* __restrict__ vb,
        const float* __restrict__ simG, const float* __restrict__ gateG,
        const float* __restrict__ Sloc, const float* __restrict__ nloc,
        const float* __restrict__ aggL, const float* __restrict__ kv_scale,
        float* __restrict__ Y, u16* __restrict__ yh, u16* __restrict__ yl) {
    int c = blockIdx.x, h = blockIdx.y;
    int tid = threadIdx.x;
    __shared__ float q_l[CH][PD], k_l[CH][PD], v_l[CH][PD], sp_l[HD][PD];
    __shared__ float a_l[CH][PD], m_l[CH][PD];
    __shared__ float sim_s[CH], gate_s[CH], mc_s[CH], ep_s[CH], gc_s[CH],
                     sc_s[CH], w_s2[CH], qs_s[CH], np_l[HD];
    __shared__ float agg_s[NC][3];
    size_t hb = (size_t)h*NC;

    for (int idx = tid; idx < CH*HD; idx += 256) {
        int i = idx >> 6, d = idx & 63;
        size_t gp = (size_t)(c*CH + i)*DM + h*HD + d;
        q_l[i][d] = qb[gp]; k_l[i][d] = kb[gp]; v_l[i][d] = vb[gp];
    }
    {
        float4 s[4] = {{0,0,0,0},{0,0,0,0},{0,0,0,0},{0,0,0,0}};
        for (int cc = 0; cc < c; ++cc) {
            const float* src = Sloc + (hb + cc)*4096 + (size_t)tid*16;
            #pragma unroll
            for (int j = 0; j < 4; ++j) {
                float4 a = *(const float4*)(src + j*4);
                s[j].x += a.x; s[j].y += a.y; s[j].z += a.z; s[j].w += a.w;
            }
        }
        int p = tid >> 2, nq = (tid & 3) * 16;
        #pragma unroll
        for (int j = 0; j < 4; ++j)
            *(float4*)&sp_l[p][nq + j*4] = s[j];
    }
    if (tid < CH) {
        sim_s[tid]  = simG[h*LSEQ + c*CH + tid];
        gate_s[tid] = gateG[h*LSEQ + c*CH + tid];
    }
    if (tid < NC*3) {
        int cc = tid / 3, f = tid - cc*3;
        agg_s[cc][f] = aggL[(hb + cc)*4 + f];
    }
    __syncthreads();

    float m_p = -INFINITY, s_p = 0.f, g_p = 0.f;
    for (int cc = 0; cc < c; ++cc) m_p = fmaxf(m_p, agg_s[cc][0]);
    for (int cc = 0; cc < c; ++cc) {
        s_p += agg_s[cc][1] * expf(agg_s[cc][0] - m_p);
        g_p += agg_s[cc][2];
    }
    float kv0 = kv_scale[0];

    if (tid < HD) {
        float nv = 0.f;
        for (int cc = 0; cc < c; ++cc)
            nv += expf(agg_s[cc][0] - m_p) * nloc[(hb + cc)*64 + tid];
        np_l[tid] = nv;
    }
    if (tid < CH) {
        int i = tid;
        float mloc = -INFINITY, gcum = 0.f;
        for (int s = 0; s <= i; ++s) { mloc = fmaxf(mloc, sim_s[s]); gcum += gate_s[s]; }
        float mc = fmaxf(m_p, mloc);
        mc_s[i] = mc;
        ep_s[i] = expf(m_p - mc);
        gc_s[i] = g_p + gcum;
        float qs = 0.f;
        for (int d = 0; d < 64; ++d) qs += q_l[i][d];
        qs_s[i] = qs;
    }
    __syncthreads();

    {
        int i = tid >> 2, sq = tid & 3;
        float mci = mc_s[i];
        #pragma unroll
        for (int jj = 0; jj < 16; ++jj) {
            int s = sq*16 + jj;
            float Mv = 0.f, Av = 0.f;
            if (s <= i) {
                Mv = expf(sim_s[s] - mci);
                float dot = 0.f;
                #pragma unroll
                for (int dq = 0; dq < 16; ++dq) {
                    float4 q4 = *(const float4*)&q_l[i][dq*4];
                    float4 v4 = *(const float4*)&v_l[s][dq*4];
                    dot += q4.x*v4.x + q4.y*v4.y + q4.z*v4.z + q4.w*v4.w;
                }
                Av = gate_s[s]*dot;
            }
            m_l[i][s] = Mv;
            a_l[i][s] = Av;
        }
    }
    __syncthreads();

    if (tid < CH) {
        int i = tid;
        float rs = 0.f;
        for (int s = 0; s < CH; ++s) rs += m_l[i][s];
        float sc = ep_s[i]*s_p + rs;
        sc_s[i] = sc;
        w_s2[i] = expf(sim_s[i] - mc_s[i]) / (sc + EPSF);
    }
    __syncthreads();

    {
        int i = tid >> 2, nq = tid & 3;
        float yb[16], ncv[16];
        #pragma unroll
        for (int j = 0; j < 16; ++j) { yb[j] = 0.f; ncv[j] = 0.f; }
        for (int p = 0; p < 64; ++p) {
            float qv = q_l[i][p];
            float av = a_l[i][p];
            float mv = m_l[i][p];
            #pragma unroll
            for (int jq = 0; jq < 4; ++jq) {
                float4 sp4 = *(const float4*)&sp_l[p][nq*16 + jq*4];
                float4 k4  = *(const float4*)&k_l[p][nq*16 + jq*4];
                float4 v4  = *(const float4*)&v_l[p][nq*16 + jq*4];
                yb[jq*4+0] += qv*sp4.x + av*k4.x;  ncv[jq*4+0] += mv*v4.x;
                yb[jq*4+1] += qv*sp4.y + av*k4.y;  ncv[jq*4+1] += mv*v4.y;
                yb[jq*4+2] += qv*sp4.z + av*k4.z;  ncv[jq*4+2] += mv*v4.z;
                yb[jq*4+3] += qv*sp4.w + av*k4.w;  ncv[jq*4+3] += mv*v4.w;
            }
        }
        float gsc   = kv0 / (gc_s[i] + EPSF);
        float invsc = 1.0f / (sc_s[i] + EPSF);
        float ep = ep_s[i], wv = w_s2[i], qs = qs_s[i];
        size_t yo = (size_t)(c*CH + i)*DM + h*HD + nq*16;
        #pragma unroll
        for (int j = 0; j < 16; ++j) {
            float Ybase = yb[j] * gsc;
            float lin   = (ep*np_l[nq*16+j] + ncv[j]) * invsc;
            float val = Ybase + (qs*lin - Ybase)*wv;
            Y[yo + j] = val;
            u16 hh = f2bf(val);
            yh[yo + j] = hh;
            yl[yo + j] = f2bf(val - bf2f(hh));
        }
    }
}

// ---------------- row 1/max(||.||,1e-12) over D=1024 ----------------
__global__ __launch_bounds__(256) void rownorm(const float* __restrict__ Y,
        float* __restrict__ rn) {
    int row = blockIdx.x;
    int tid = threadIdx.x;
    float4 v = *(const float4*)&Y[(size_t)row*DM + tid*4];
    float ss = v.x*v.x + v.y*v.y + v.z*v.z + v.w*v.w;
    #pragma unroll
    for (int off = 32; off >= 1; off >>= 1) ss += __shfl_xor(ss, off);
    __shared__ float wsum[4];
    if ((tid & 63) == 0) wsum[tid >> 6] = ss;
    __syncthreads();
    if (tid == 0) {
        float tot = wsum[0] + wsum[1] + wsum[2] + wsum[3];
        rn[row] = 1.0f / fmaxf(sqrtf(tot), 1e-12f);
    }
}

extern "C" void kernel_launch(void* const* d_in, const int* in_sizes, int n_in,
                              void* d_out, int out_size, void* d_ws, size_t ws_size,
                              hipStream_t stream) {
    const float* x      = (const float*)d_in[0];
    const float* conv_w = (const float*)d_in[1];
    const float* conv_b = (const float*)d_in[2];
    const float* mphi_w = (const float*)d_in[3];
    const float* mphi_b = (const float*)d_in[4];
    const float* wq_w   = (const float*)d_in[5];
    const float* wq_b   = (const float*)d_in[6];
    const float* wk_w   = (const float*)d_in[7];
    const float* wk_b   = (const float*)d_in[8];
    const float* wv_w   = (const float*)d_in[9];
    const float* wv_b   = (const float*)d_in[10];
    const float* wo_w   = (const float*)d_in[11];
    const float* wo_b   = (const float*)d_in[12];
    const float* wgz_w  = (const float*)d_in[13];
    const float* wgz_b  = (const float*)d_in[14];
    const float* kv_sc  = (const float*)d_in[15];
    const float* qk_sc  = (const float*)d_in[16];
    float* out = (float*)d_out;

    // ---- workspace layout (MB offsets), peak 100 MB ----
    char* p = (char*)d_ws;
    u16*  xp_h    = (u16*)p;                      // [0,4)   1026x1024 u16 (2.1MB)
    u16*  xp_l    = (u16*)(p + 4194304);          // [4,8)
    float* beff   = (float*)(p + 8388608);        // [8] 4KB
    u16*  wt_h    = (u16*)(p + 9437184);          // [9,15)  1024x3072 u16
    u16*  wt_l    = (u16*)(p + 15728640);         // [15,21)
    float* simG   = (float*)(p + 22020096);       // [21,24) small buffers
    float* gateG  = (float*)(p + 22085632);
    float* nlocp  = (float*)(p + 22151168);
    float* aggL   = (float*)(p + 22216704);
    float* rn     = (float*)(p + 22220800);
    u16*  wqkvT_h = (u16*)(p + 25165824);         // [24,30)
    u16*  wqkvT_l = (u16*)(p + 31457280);         // [30,36)
    u16*  woT_h   = (u16*)(p + 37748736);         // [36,38)
    u16*  woT_l   = (u16*)(p + 39845888);         // [38,40)
    float* qkvPart= (float*)(p + 41943040);       // [40,64)  2 x 12MB
    float* Ybuf   = (float*)(p + 41943040);       // [40,44)  after reduce_qkv
    u16*  y_h     = (u16*)(p + 46137344);         // [44,46)
    u16*  y_l     = (u16*)(p + 48234496);         // [46,48)
    float* woPart = (float*)(p + 50331648);       // [48,64)  4 x 4MB (after attn_out)
    float* g1Part = (float*)(p + 67108864);       // [64,96)  8 x 4MB
    float* qb     = (float*)(p + 67108864);       // [64,68)  after reduce_xt8
    float* kb     = (float*)(p + 71303168);       // [68,72)
    float* vb     = (float*)(p + 75497472);       // [72,76)
    float* Sloc   = (float*)(p + 79691776);       // [76,80)
    u16*  xt_h    = (u16*)(p + 100663296);        // [96,98)
    u16*  xt_l    = (u16*)(p + 102760448);        // [98,100)

    // x split (+ beff zero), conv⊗mphi weight fold
    xsplit<<<4104, 256, 0, stream>>>(x, xp_h, xp_l, beff);
    wtilde<<<dim3(32, 32), 256, 0, stream>>>(mphi_w, conv_w, conv_b, wt_h, wt_l, beff);

    // GEMM1 (conv-fused, K=3072, split-K=8) then reduce + biases + bf16 split
    gemm_conv3<<<dim3(8, 8, 8), 512, 0, stream>>>(xp_h, xp_l, wt_h, wt_l, g1Part);
    reduce_xt8<<<1024, 256, 0, stream>>>(g1Part, mphi_b, beff, xt_h, xt_l);

    // QKV + WO weight transposes
    wconv_t4<<<dim3(32, 32, 4), 256, 0, stream>>>(wq_w, wk_w, wv_w, wo_w,
            wqkvT_h, wqkvT_l, woT_h, woT_l);

    // QKV fused (N=3072, split-K=2); reduce adds bias + per-head norm
    gemm_bf16x3_128<<<dim3(24, 8, 2), 512, 0, stream>>>(xt_h, xt_l, wqkvT_h, wqkvT_l,
            qkvPart, 1024, 3072, 1024);
    reduce_qkv<<<1024, 256, 0, stream>>>(qkvPart, wq_b, wk_b, wv_b, qb, kb, vb);

    attn_local<<<dim3(NC, NH), 256, 0, stream>>>(qb, kb, vb, wgz_w, wgz_b, kv_sc, qk_sc,
                                                 simG, gateG, Sloc, nlocp, aggL);
    attn_out<<<dim3(NC, NH), 256, 0, stream>>>(qb, kb, vb, simG, gateG, Sloc, nlocp, aggL,
                                               kv_sc, Ybuf, y_h, y_l);
    rownorm<<<1024, 256, 0, stream>>>(Ybuf, rn);

    // WO (split-K=4); reduce applies rowscale + bias
    gemm_bf16x3_128<<<dim3(8, 8, 4), 512, 0, stream>>>(y_h, y_l, woT_h, woT_l,
            woPart, 1024, 1024, 1024);
    reduce_out<<<1024, 256, 0, stream>>>(woPart, 4, rn, wo_b, out);
}

// Round 8
// 285.431 us; speedup vs baseline: 1.2826x; 1.0039x over previous
//
#include <hip/hip_runtime.h>
#include <math.h>

// Problem constants (B=1)
#define LSEQ 1024
#define DM   1024
#define NH   16
#define HD   64
#define KEXP 8
#define NC   16   // chunks
#define CH   64   // chunk length
#define EPSF 1e-5f
#define PD   68   // LDS row pad (words) for attn kernels
#define WPD  65

typedef unsigned short u16;
typedef unsigned int   u32;
typedef __attribute__((ext_vector_type(8))) short short8;   // 8 bf16 (4 VGPRs)
typedef __attribute__((ext_vector_type(4))) float f32x4;

__device__ __forceinline__ u16 f2bf(float f) {
    u32 u = __float_as_uint(f);
    return (u16)((u + 0x7fffu + ((u >> 16) & 1u)) >> 16);   // RNE
}
__device__ __forceinline__ float bf2f(u16 h) {
    return __uint_as_float(((u32)h) << 16);
}

// ---------------- x -> zero-padded (2 rows) bf16 hi/lo split; also zeroes beff ----------------
__global__ __launch_bounds__(256) void xsplit(const float* __restrict__ x,
        u16* __restrict__ xph, u16* __restrict__ xpl, float* __restrict__ beff) {
    int g = blockIdx.x * 256 + threadIdx.x;   // [0, 1026*1024)
    int row = g >> 10, d = g & 1023;
    float val = (row < 2) ? 0.f : x[(size_t)(row - 2) * 1024 + d];
    u16 h = f2bf(val);
    xph[g] = h;
    xpl[g] = f2bf(val - bf2f(h));
    if (g < 1024) beff[g] = 0.f;
}

// ---------------- W~_j[d,n] = sum_kk cw[d*8+kk, j] * mphi[kk*1024+d, n]  (+ conv-bias fold) ----
__global__ __launch_bounds__(256) void wtilde(const float* __restrict__ mphi,
        const float* __restrict__ cw, const float* __restrict__ cb,
        u16* __restrict__ wth, u16* __restrict__ wtl, float* __restrict__ beff) {
    __shared__ float wl[3][32][33];
    __shared__ float cbp[8][33];
    int n0 = blockIdx.x * 32, d0 = blockIdx.y * 32;
    int tx = threadIdx.x & 31, ty = threadIdx.x >> 5;
    float cbacc = 0.f;
    #pragma unroll
    for (int k2 = 0; k2 < 4; ++k2) {
        int d = d0 + ty + 8*k2;
        int n = n0 + tx;
        float s0 = 0.f, s1 = 0.f, s2 = 0.f, cbs = 0.f;
        #pragma unroll
        for (int kk = 0; kk < 8; ++kk) {
            float mv = mphi[((size_t)(kk*1024 + d))*1024 + n];
            const float* cwp = cw + (size_t)(d*8 + kk)*3;
            s0 += cwp[0]*mv; s1 += cwp[1]*mv; s2 += cwp[2]*mv;
            cbs += cb[d*8 + kk]*mv;
        }
        wl[0][ty+8*k2][tx] = s0;
        wl[1][ty+8*k2][tx] = s1;
        wl[2][ty+8*k2][tx] = s2;
        cbacc += cbs;
    }
    cbp[ty][tx] = cbacc;
    __syncthreads();
    #pragma unroll
    for (int k2 = 0; k2 < 4; ++k2) {
        int nn = n0 + ty + 8*k2;
        #pragma unroll
        for (int j = 0; j < 3; ++j) {
            float v = wl[j][tx][ty+8*k2];
            u16 h = f2bf(v);
            size_t o = (size_t)nn*3072 + j*1024 + d0 + tx;
            wth[o] = h;
            wtl[o] = f2bf(v - bf2f(h));
        }
    }
    if (ty == 0) {
        float s = 0.f;
        #pragma unroll
        for (int r = 0; r < 8; ++r) s += cbp[r][tx];
        atomicAdd(beff + n0 + tx, s);
    }
}

// ---------------- merged 4-weight transpose (1024x1024 each), z picks source/dest ----------------
__global__ __launch_bounds__(256) void wconv_t4(const float* __restrict__ W0,
        const float* __restrict__ W1, const float* __restrict__ W2,
        const float* __restrict__ W3,
        u16* __restrict__ Tqkv_h, u16* __restrict__ Tqkv_l,
        u16* __restrict__ To_h, u16* __restrict__ To_l) {
    __shared__ float t[32][33];
    int z = blockIdx.z;
    const float* W = (z == 0) ? W0 : (z == 1) ? W1 : (z == 2) ? W2 : W3;
    u16* Th = (z < 3) ? Tqkv_h + (size_t)z*1048576 : To_h;
    u16* Tl = (z < 3) ? Tqkv_l + (size_t)z*1048576 : To_l;
    int c0 = blockIdx.x*32, r0 = blockIdx.y*32;
    int tx = threadIdx.x & 31, ty = threadIdx.x >> 5;
    #pragma unroll
    for (int k2 = 0; k2 < 4; ++k2)
        t[ty+8*k2][tx] = W[(size_t)(r0+ty+8*k2)*1024 + c0+tx];
    __syncthreads();
    #pragma unroll
    for (int k2 = 0; k2 < 4; ++k2) {
        float v = t[tx][ty+8*k2];
        u16 h = f2bf(v);
        size_t o = (size_t)(c0+ty+8*k2)*1024 + r0+tx;
        Th[o] = h;
        Tl[o] = f2bf(v - bf2f(h));
    }
}

#define MF(a_,b_,c_) c_ = __builtin_amdgcn_mfma_f32_16x16x32_bf16(a_, b_, c_, 0, 0, 0)

// ---------------- conv-fused GEMM1: xt_part = [x(t-2)|x(t-1)|x(t)] @ W~  (K=3072) ----------------
__global__ __launch_bounds__(512, 4) void gemm_conv3(
        const u16* __restrict__ xph, const u16* __restrict__ xpl,
        const u16* __restrict__ Bth, const u16* __restrict__ Btl,
        float* __restrict__ Cp) {
    __shared__ u16 Ash[128][72];
    __shared__ u16 Asl[128][72];
    __shared__ u16 Bsh[128][72];
    __shared__ u16 Bsl[128][72];

    const int tid = threadIdx.x;
    const int z = blockIdx.z, Z = gridDim.z;
    const int mpan = ((blockIdx.x >> 1) << 1) + (blockIdx.y >> 2);
    const int npan = ((blockIdx.x & 1) << 2) + (blockIdx.y & 3);
    const int m0 = mpan * 128, n0 = npan * 128;
    const int lane = tid & 63, w = tid >> 6;
    const int wm = w >> 2, wn = w & 3;
    const int fr = lane & 15, kh = lane >> 4;

    const int r0 = tid >> 3;
    const int sl = (tid + (tid >> 3)) & 7;
    const int sc = sl * 8;
    const size_t bO0 = (size_t)(n0 + r0)      * 3072 + sc;
    const size_t bO1 = (size_t)(n0 + r0 + 64) * 3072 + sc;

    const int ktiles = 48;
    const int t0 = (ktiles * z) / Z, t1 = (ktiles * (z + 1)) / Z;

    uint4 ra0h, ra0l, ra1h, ra1l, rb0h, rb0l, rb1h, rb1l;
    f32x4 acc[4][2];
    #pragma unroll
    for (int mi = 0; mi < 4; ++mi)
        #pragma unroll
        for (int ni = 0; ni < 2; ++ni) acc[mi][ni] = (f32x4){0,0,0,0};

#define LOADC3(t_) { int j_ = (t_) >> 4; int doff_ = ((t_) & 15) * 64;   \
        size_t ao_ = ((size_t)(m0 + r0 + j_) << 10) + doff_ + sc;        \
        ra0h = *(const uint4*)(xph + ao_);                               \
        ra0l = *(const uint4*)(xpl + ao_);                               \
        ra1h = *(const uint4*)(xph + ao_ + 65536);                       \
        ra1l = *(const uint4*)(xpl + ao_ + 65536);                       \
        size_t bo_ = (size_t)(t_) * 64;                                  \
        rb0h = *(const uint4*)(Bth + bO0 + bo_);                         \
        rb0l = *(const uint4*)(Btl + bO0 + bo_);                         \
        rb1h = *(const uint4*)(Bth + bO1 + bo_);                         \
        rb1l = *(const uint4*)(Btl + bO1 + bo_); }
#define WRLDS128() {                                                     \
        *(uint4*)&Ash[r0   ][sc] = ra0h; *(uint4*)&Asl[r0   ][sc] = ra0l; \
        *(uint4*)&Ash[r0+64][sc] = ra1h; *(uint4*)&Asl[r0+64][sc] = ra1l; \
        *(uint4*)&Bsh[r0   ][sc] = rb0h; *(uint4*)&Bsl[r0   ][sc] = rb0l; \
        *(uint4*)&Bsh[r0+64][sc] = rb1h; *(uint4*)&Bsl[r0+64][sc] = rb1l; }

    LOADC3(t0);
    WRLDS128();
    __syncthreads();

    for (int t = t0; t < t1; ++t) {
        if (t + 1 < t1) LOADC3(t + 1);
        #pragma unroll
        for (int ks = 0; ks < 2; ++ks) {
            const int ko = ks*32 + kh*8;
            short8 a_h[4], a_l[4], b_h[2], b_l[2];
            #pragma unroll
            for (int mi = 0; mi < 4; ++mi) {
                a_h[mi] = *(const short8*)&Ash[wm*64 + mi*16 + fr][ko];
                a_l[mi] = *(const short8*)&Asl[wm*64 + mi*16 + fr][ko];
            }
            #pragma unroll
            for (int ni = 0; ni < 2; ++ni) {
                b_h[ni] = *(const short8*)&Bsh[wn*32 + ni*16 + fr][ko];
                b_l[ni] = *(const short8*)&Bsl[wn*32 + ni*16 + fr][ko];
            }
            #pragma unroll
            for (int mi = 0; mi < 4; ++mi)
                #pragma unroll
                for (int ni = 0; ni < 2; ++ni) {
                    MF(a_h[mi], b_h[ni], acc[mi][ni]);
                    MF(a_h[mi], b_l[ni], acc[mi][ni]);
                    MF(a_l[mi], b_h[ni], acc[mi][ni]);
                }
        }
        __syncthreads();
        if (t + 1 < t1) {
            WRLDS128();
            __syncthreads();
        }
    }
#undef LOADC3
#undef WRLDS128

    float* Cz = Cp + (size_t)z * 1048576;
    #pragma unroll
    for (int mi = 0; mi < 4; ++mi)
        #pragma unroll
        for (int ni = 0; ni < 2; ++ni) {
            const int col = n0 + wn*32 + ni*16 + fr;
            #pragma unroll
            for (int rr = 0; rr < 4; ++rr) {
                const int row = m0 + wm*64 + mi*16 + kh*4 + rr;
                Cz[(size_t)row * 1024 + col] = acc[mi][ni][rr];
            }
        }
}

// ---------------- generic 128x128 split-K MFMA GEMM (bf16 hi/lo ×3), fp32 partials ----------------
__global__ __launch_bounds__(512, 4) void gemm_bf16x3_128(
        const u16* __restrict__ Ah, const u16* __restrict__ Al,
        const u16* __restrict__ Bth, const u16* __restrict__ Btl,
        float* __restrict__ Cp, int M, int N, int K) {
    __shared__ u16 Ash[128][72];
    __shared__ u16 Asl[128][72];
    __shared__ u16 Bsh[128][72];
    __shared__ u16 Bsl[128][72];

    const int tid = threadIdx.x;
    const int z = blockIdx.z, Z = gridDim.z;
    int mpan, npan;
    if (gridDim.x == 8 && gridDim.y == 8) {
        mpan = ((blockIdx.x >> 1) << 1) + (blockIdx.y >> 2);
        npan = ((blockIdx.x & 1) << 2) + (blockIdx.y & 3);
    } else {
        const int id = blockIdx.y * gridDim.x + blockIdx.x;
        mpan = id % gridDim.y;
        npan = id / gridDim.y;
    }
    const int m0 = mpan * 128, n0 = npan * 128;
    const int lane = tid & 63, w = tid >> 6;
    const int wm = w >> 2, wn = w & 3;
    const int fr = lane & 15, kh = lane >> 4;

    const int r0 = tid >> 3;
    const int sl = (tid + (tid >> 3)) & 7;
    const int sc = sl * 8;
    const size_t aO0 = (size_t)(m0 + r0)      * K + sc;
    const size_t aO1 = (size_t)(m0 + r0 + 64) * K + sc;
    const size_t bO0 = (size_t)(n0 + r0)      * K + sc;
    const size_t bO1 = (size_t)(n0 + r0 + 64) * K + sc;

    const int ktiles = K >> 6;
    const int t0 = (ktiles * z) / Z, t1 = (ktiles * (z + 1)) / Z;

    uint4 ra0h, ra0l, ra1h, ra1l, rb0h, rb0l, rb1h, rb1l;
    f32x4 acc[4][2];
    #pragma unroll
    for (int mi = 0; mi < 4; ++mi)
        #pragma unroll
        for (int ni = 0; ni < 2; ++ni) acc[mi][ni] = (f32x4){0,0,0,0};

#define LOADG128(t_) { size_t ko_ = (size_t)(t_) * 64;                  \
        ra0h = *(const uint4*)(Ah  + aO0 + ko_);                        \
        ra0l = *(const uint4*)(Al  + aO0 + ko_);                        \
        ra1h = *(const uint4*)(Ah  + aO1 + ko_);                        \
        ra1l = *(const uint4*)(Al  + aO1 + ko_);                        \
        rb0h = *(const uint4*)(Bth + bO0 + ko_);                        \
        rb0l = *(const uint4*)(Btl + bO0 + ko_);                        \
        rb1h = *(const uint4*)(Bth + bO1 + ko_);                        \
        rb1l = *(const uint4*)(Btl + bO1 + ko_); }
#define WRLDS128() {                                                    \
        *(uint4*)&Ash[r0   ][sc] = ra0h; *(uint4*)&Asl[r0   ][sc] = ra0l; \
        *(uint4*)&Ash[r0+64][sc] = ra1h; *(uint4*)&Asl[r0+64][sc] = ra1l; \
        *(uint4*)&Bsh[r0   ][sc] = rb0h; *(uint4*)&Bsl[r0   ][sc] = rb0l; \
        *(uint4*)&Bsh[r0+64][sc] = rb1h; *(uint4*)&Bsl[r0+64][sc] = rb1l; }

    LOADG128(t0);
    WRLDS128();
    __syncthreads();

    for (int t = t0; t < t1; ++t) {
        if (t + 1 < t1) LOADG128(t + 1);
        #pragma unroll
        for (int ks = 0; ks < 2; ++ks) {
            const int ko = ks*32 + kh*8;
            short8 a_h[4], a_l[4], b_h[2], b_l[2];
            #pragma unroll
            for (int mi = 0; mi < 4; ++mi) {
                a_h[mi] = *(const short8*)&Ash[wm*64 + mi*16 + fr][ko];
                a_l[mi] = *(const short8*)&Asl[wm*64 + mi*16 + fr][ko];
            }
            #pragma unroll
            for (int ni = 0; ni < 2; ++ni) {
                b_h[ni] = *(const short8*)&Bsh[wn*32 + ni*16 + fr][ko];
                b_l[ni] = *(const short8*)&Bsl[wn*32 + ni*16 + fr][ko];
            }
            #pragma unroll
            for (int mi = 0; mi < 4; ++mi)
                #pragma unroll
                for (int ni = 0; ni < 2; ++ni) {
                    MF(a_h[mi], b_h[ni], acc[mi][ni]);
                    MF(a_h[mi], b_l[ni], acc[mi][ni]);
                    MF(a_l[mi], b_h[ni], acc[mi][ni]);
                }
        }
        __syncthreads();
        if (t + 1 < t1) {
            WRLDS128();
            __syncthreads();
        }
    }
#undef LOADG128
#undef WRLDS128

    float* Cz = Cp + (size_t)z * M * N;
    #pragma unroll
    for (int mi = 0; mi < 4; ++mi)
        #pragma unroll
        for (int ni = 0; ni < 2; ++ni) {
            const int col = n0 + wn*32 + ni*16 + fr;
            #pragma unroll
            for (int rr = 0; rr < 4; ++rr) {
                const int row = m0 + wm*64 + mi*16 + kh*4 + rr;
                Cz[(size_t)row * N + col] = acc[mi][ni][rr];
            }
        }
}

// ---------------- reduce 8 partials + (mphi_b + beff) -> xt hi/lo ----------------
__global__ __launch_bounds__(256) void reduce_xt8(const float* __restrict__ Cp,
        const float* __restrict__ bias, const float* __restrict__ beff,
        u16* __restrict__ xh, u16* __restrict__ xl) {
    int g = blockIdx.x * 256 + threadIdx.x;   // 262144
    int idx = g * 4;
    float4 bv = *(const float4*)(bias + (idx & 1023));
    float4 be = *(const float4*)(beff + (idx & 1023));
    float v[4] = {bv.x + be.x, bv.y + be.y, bv.z + be.z, bv.w + be.w};
    #pragma unroll
    for (int s = 0; s < 8; ++s) {
        float4 a = *(const float4*)(Cp + (size_t)s*1048576 + idx);
        v[0] += a.x; v[1] += a.y; v[2] += a.z; v[3] += a.w;
    }
    ushort4 hh, ll;
    u16* hp = (u16*)&hh; u16* lp = (u16*)&ll;
    #pragma unroll
    for (int j = 0; j < 4; ++j) {
        u16 h = f2bf(v[j]);
        hp[j] = h;
        lp[j] = f2bf(v[j] - bf2f(h));
    }
    *(ushort4*)(xh + idx) = hh;
    *(ushort4*)(xl + idx) = ll;
}

// ---------------- reduce QKV partials (2 x 1024x3072) + bias + per-head normalize ----------------
__global__ __launch_bounds__(256) void reduce_qkv(const float* __restrict__ Cp,
        const float* __restrict__ qbias, const float* __restrict__ kbias,
        const float* __restrict__ vbias,
        float* __restrict__ qo, float* __restrict__ ko, float* __restrict__ vo) {
    int row = blockIdx.x;
    int t = threadIdx.x;
    const float* biases[3] = {qbias, kbias, vbias};
    float* outs[3] = {qo, ko, vo};
    int col = t * 4;
    #pragma unroll
    for (int s = 0; s < 3; ++s) {
        size_t o = (size_t)row*3072 + (size_t)s*1024 + col;
        float4 a = *(const float4*)(Cp + o);
        float4 b = *(const float4*)(Cp + 3145728 + o);
        float4 bv = *(const float4*)(biases[s] + col);
        float v0 = a.x + b.x + bv.x, v1 = a.y + b.y + bv.y;
        float v2 = a.z + b.z + bv.z, v3 = a.w + b.w + bv.w;
        float ss = v0*v0 + v1*v1 + v2*v2 + v3*v3;
        #pragma unroll
        for (int off = 1; off < 16; off <<= 1) ss += __shfl_xor(ss, off);
        float scl = 1.0f / fmaxf(sqrtf(ss), 1e-12f);
        float4 o4 = {v0*scl, v1*scl, v2*scl, v3*scl};
        *(float4*)(outs[s] + (size_t)row*1024 + col) = o4;
    }
}

// ---------------- reduce ns partials, apply rowscale + bias -> fp32 out ----------------
__global__ __launch_bounds__(256) void reduce_out(const float* __restrict__ Cp,
        int ns, const float* __restrict__ rowscale, const float* __restrict__ bias,
        float* __restrict__ out) {
    int g = blockIdx.x * 256 + threadIdx.x;
    int idx = g * 4;
    float s0 = 0.f, s1 = 0.f, s2 = 0.f, s3 = 0.f;
    for (int s = 0; s < ns; ++s) {
        float4 a = *(const float4*)(Cp + (size_t)s*1048576 + idx);
        s0 += a.x; s1 += a.y; s2 += a.z; s3 += a.w;
    }
    float4 bv = *(const float4*)(bias + (idx & 1023));
    float rs = rowscale[idx >> 10];
    float4 o = {s0*rs + bv.x, s1*rs + bv.y, s2*rs + bv.z, s3*rs + bv.w};
    *(float4*)(out + idx) = o;
}

// ---------------- attention: per-(head,chunk) locals ----------------
__global__ __launch_bounds__(256) void attn_local(const float* __restrict__ qb,
        const float* __restrict__ kb, const float* __restrict__ vb,
        const float* __restrict__ wgz_w, const float* __restrict__ wgz_b,
        const float* __restrict__ kv_scale, const float* __restrict__ qk_scale,
        float* __restrict__ simG, float* __restrict__ gateG,
        float* __restrict__ Sloc, float* __restrict__ nloc, float* __restrict__ aggL) {
    int c = blockIdx.x, h = blockIdx.y;
    int tid = threadIdx.x;
    __shared__ float q_l[CH][PD], k_l[CH][PD], v_l[CH][PD];
    __shared__ float wg_l[HD][WPD];
    __shared__ float sim_s[CH], gate_s[CH], e_s[CH];

    for (int idx = tid; idx < CH*HD; idx += 256) {
        int i = idx >> 6, d = idx & 63;
        size_t gp = (size_t)(c*CH + i)*DM + h*HD + d;
        q_l[i][d] = qb[gp]; k_l[i][d] = kb[gp]; v_l[i][d] = vb[gp];
        wg_l[i][d] = wgz_w[idx];
    }
    __syncthreads();

    int si = tid >> 2, part = tid & 3;
    float qk_h = qk_scale[h];
    float kv0  = kv_scale[0];

    float sum = 0.f;
    #pragma unroll
    for (int d = 0; d < 16; ++d) sum += q_l[si][part*16+d]*k_l[si][part*16+d];
    sum += __shfl_xor(sum, 1); sum += __shfl_xor(sum, 2);

    float gpart = 0.f;
    for (int pp = 0; pp < 16; ++pp) {
        int p = part*16 + pp;
        float u = 0.f;
        for (int n = 0; n < 64; ++n) u += wg_l[p][n]*k_l[si][n];
        gpart += v_l[si][p]*u;
    }
    gpart += __shfl_xor(gpart, 1); gpart += __shfl_xor(gpart, 2);

    if (part == 0) {
        sim_s[si] = sum * qk_h;
        float raw = kv0*gpart + wgz_b[0];
        gate_s[si] = ((raw > 0.f) ? raw : 0.01f*raw) + EPSF;
    }
    __syncthreads();

    if (tid < CH) {
        simG[h*LSEQ + c*CH + tid]  = sim_s[tid];
        gateG[h*LSEQ + c*CH + tid] = gate_s[tid];
    }

    {
        int p = tid >> 2, nq = tid & 3;
        float acc[16];
        #pragma unroll
        for (int j = 0; j < 16; ++j) acc[j] = 0.f;
        for (int s = 0; s < CH; ++s) {
            float gv = gate_s[s]*v_l[s][p];
            #pragma unroll
            for (int j = 0; j < 16; ++j) acc[j] += gv * k_l[s][nq*16+j];
        }
        size_t so = ((size_t)h*NC + c)*4096 + (size_t)p*64 + nq*16;
        #pragma unroll
        for (int j = 0; j < 16; ++j) Sloc[so+j] = acc[j];
    }

    float m_loc = -INFINITY, s_loc = 0.f, g_sum = 0.f;
    if (tid < 64) {
        float mv = sim_s[tid];
        m_loc = mv;
        #pragma unroll
        for (int off = 32; off >= 1; off >>= 1) m_loc = fmaxf(m_loc, __shfl_xor(m_loc, off));
        float e = expf(mv - m_loc);
        e_s[tid] = e;
        s_loc = e;
        #pragma unroll
        for (int off = 32; off >= 1; off >>= 1) s_loc += __shfl_xor(s_loc, off);
        float gv = gate_s[tid];
        g_sum = gv;
        #pragma unroll
        for (int off = 32; off >= 1; off >>= 1) g_sum += __shfl_xor(g_sum, off);
    }
    __syncthreads();
    if (tid < 64) {
        float nl = 0.f;
        for (int s = 0; s < CH; ++s) nl += e_s[s]*v_l[s][tid];
        nloc[((size_t)h*NC + c)*64 + tid] = nl;
        if (tid == 0) {
            size_t ao = ((size_t)h*NC + c)*4;
            aggL[ao+0] = m_loc; aggL[ao+1] = s_loc; aggL[ao+2] = g_sum;
        }
    }
}

// ---------------- per-(head,chunk,half) outputs; 32 rows/block, 2 blocks per (c,h) ----------------
// grid (NC, NH, 2). Conflict-free A/M mapping: thread (i=tid>>3, sg=tid&7), s = jj*8+sg
// (8 consecutive LDS rows per lane-group => distinct bank quads).
__global__ __launch_bounds__(256) void attn_out(const float* __restrict__ qb,
        const float* __restrict__ kb, const float* __restrict__ vb,
        const float* __restrict__ simG, const float* __restrict__ gateG,
        const float* __restrict__ Sloc, const float* __restrict__ nloc,
        const float* __restrict__ aggL, const float* __restrict__ kv_scale,
        float* __restrict__ Y, u16* __restrict__ yh, u16* __restrict__ yl) {
    int c = blockIdx.x, h = blockIdx.y;
    int i0 = blockIdx.z * 32;
    int tid = threadIdx.x;
    __shared__ float q_l[32][PD], k_l[CH][PD], v_l[CH][PD], sp_l[HD][PD];
    __shared__ float a_l[32][PD], m_l[32][PD];
    __shared__ float sim_s[CH], gate_s[CH], np_l[HD];
    __shared__ float mc_s[32], ep_s[32], gc_s[32], sc_s[32], w_s2[32], qs_s[32];
    __shared__ float agg_s[NC][3];
    size_t hb = (size_t)h*NC;

    for (int idx = tid; idx < CH*HD; idx += 256) {
        int i = idx >> 6, d = idx & 63;
        size_t gp = (size_t)(c*CH + i)*DM + h*HD + d;
        k_l[i][d] = kb[gp]; v_l[i][d] = vb[gp];
    }
    for (int idx = tid; idx < 32*HD; idx += 256) {
        int i = idx >> 6, d = idx & 63;
        q_l[i][d] = qb[(size_t)(c*CH + i0 + i)*DM + h*HD + d];
    }
    {   // Spre = sum_{cc<c} Sloc[h][cc]  (full 64x64, parallel, L2-hot)
        float4 s[4] = {{0,0,0,0},{0,0,0,0},{0,0,0,0},{0,0,0,0}};
        for (int cc = 0; cc < c; ++cc) {
            const float* src = Sloc + (hb + cc)*4096 + (size_t)tid*16;
            #pragma unroll
            for (int j = 0; j < 4; ++j) {
                float4 a = *(const float4*)(src + j*4);
                s[j].x += a.x; s[j].y += a.y; s[j].z += a.z; s[j].w += a.w;
            }
        }
        int p = tid >> 2, nq = (tid & 3) * 16;
        #pragma unroll
        for (int j = 0; j < 4; ++j)
            *(float4*)&sp_l[p][nq + j*4] = s[j];
    }
    if (tid < CH) {
        sim_s[tid]  = simG[h*LSEQ + c*CH + tid];
        gate_s[tid] = gateG[h*LSEQ + c*CH + tid];
    }
    if (tid < NC*3) {
        int cc = tid / 3, f = tid - cc*3;
        agg_s[cc][f] = aggL[(hb + cc)*4 + f];
    }
    __syncthreads();

    // prefix scalars (redundant per-thread; c<=15 iterations)
    float m_p = -INFINITY, s_p = 0.f, g_p = 0.f;
    for (int cc = 0; cc < c; ++cc) m_p = fmaxf(m_p, agg_s[cc][0]);
    for (int cc = 0; cc < c; ++cc) {
        s_p += agg_s[cc][1] * expf(agg_s[cc][0] - m_p);
        g_p += agg_s[cc][2];
    }
    float kv0 = kv_scale[0];

    if (tid < HD) {   // npre
        float nv = 0.f;
        for (int cc = 0; cc < c; ++cc)
            nv += expf(agg_s[cc][0] - m_p) * nloc[(hb + cc)*64 + tid];
        np_l[tid] = nv;
    }
    if (tid < 32) {   // per-row within-chunk prefixes (global row ig = i0+tid)
        int ig = i0 + tid;
        float mloc = -INFINITY, gcum = 0.f;
        for (int s = 0; s <= ig; ++s) { mloc = fmaxf(mloc, sim_s[s]); gcum += gate_s[s]; }
        float mc = fmaxf(m_p, mloc);
        mc_s[tid] = mc;
        ep_s[tid] = expf(m_p - mc);
        gc_s[tid] = g_p + gcum;
        float qs = 0.f;
        for (int d = 0; d < 64; ++d) qs += q_l[tid][d];
        qs_s[tid] = qs;
    }
    __syncthreads();

    {   // M[i][s], A[i][s] = (s<=ig) ? gates[s]*(q_i . v_s) : 0;  s = jj*8 + sg
        int i = tid >> 3, sg = tid & 7;
        int ig = i0 + i;
        float mci = mc_s[i];
        #pragma unroll
        for (int jj = 0; jj < 8; ++jj) {
            int s = jj*8 + sg;
            float Mv = 0.f, Av = 0.f;
            if (s <= ig) {
                Mv = expf(sim_s[s] - mci);
                float dot = 0.f;
                #pragma unroll
                for (int dq = 0; dq < 16; ++dq) {
                    float4 q4 = *(const float4*)&q_l[i][dq*4];
                    float4 v4 = *(const float4*)&v_l[s][dq*4];
                    dot += q4.x*v4.x + q4.y*v4.y + q4.z*v4.z + q4.w*v4.w;
                }
                Av = gate_s[s]*dot;
            }
            m_l[i][s] = Mv;
            a_l[i][s] = Av;
        }
    }
    __syncthreads();

    if (tid < 32) {   // row sums of M -> s_c, w
        int ig = i0 + tid;
        float rs = 0.f;
        for (int s = 0; s < CH; ++s) rs += m_l[tid][s];
        float sc = ep_s[tid]*s_p + rs;
        sc_s[tid] = sc;
        w_s2[tid] = expf(sim_s[ig] - mc_s[tid]) / (sc + EPSF);
    }
    __syncthreads();

    {   // outputs: thread (i, nq), 8 columns nq*8..nq*8+7
        int i = tid >> 3, nq = tid & 7;
        float yb[8], ncv[8];
        #pragma unroll
        for (int j = 0; j < 8; ++j) { yb[j] = 0.f; ncv[j] = 0.f; }
        for (int p = 0; p < 64; ++p) {
            float qv = q_l[i][p];
            float av = a_l[i][p];
            float mv = m_l[i][p];
            #pragma unroll
            for (int jq = 0; jq < 2; ++jq) {
                float4 sp4 = *(const float4*)&sp_l[p][nq*8 + jq*4];
                float4 k4  = *(const float4*)&k_l[p][nq*8 + jq*4];
                float4 v4  = *(const float4*)&v_l[p][nq*8 + jq*4];
                yb[jq*4+0] += qv*sp4.x + av*k4.x;  ncv[jq*4+0] += mv*v4.x;
                yb[jq*4+1] += qv*sp4.y + av*k4.y;  ncv[jq*4+1] += mv*v4.y;
                yb[jq*4+2] += qv*sp4.z + av*k4.z;  ncv[jq*4+2] += mv*v4.z;
                yb[jq*4+3] += qv*sp4.w + av*k4.w;  ncv[jq*4+3] += mv*v4.w;
            }
        }
        float gsc   = kv0 / (gc_s[i] + EPSF);
        float invsc = 1.0f / (sc_s[i] + EPSF);
        float ep = ep_s[i], wv = w_s2[i], qs = qs_s[i];
        size_t yo = (size_t)(c*CH + i0 + i)*DM + h*HD + nq*8;
        #pragma unroll
        for (int j = 0; j < 8; ++j) {
            float Ybase = yb[j] * gsc;
            float lin   = (ep*np_l[nq*8+j] + ncv[j]) * invsc;
            float val = Ybase + (qs*lin - Ybase)*wv;
            Y[yo + j] = val;
            u16 hh = f2bf(val);
            yh[yo + j] = hh;
            yl[yo + j] = f2bf(val - bf2f(hh));
        }
    }
}

// ---------------- row 1/max(||.||,1e-12) over D=1024 ----------------
__global__ __launch_bounds__(256) void rownorm(const float* __restrict__ Y,
        float* __restrict__ rn) {
    int row = blockIdx.x;
    int tid = threadIdx.x;
    float4 v = *(const float4*)&Y[(size_t)row*DM + tid*4];
    float ss = v.x*v.x + v.y*v.y + v.z*v.z + v.w*v.w;
    #pragma unroll
    for (int off = 32; off >= 1; off >>= 1) ss += __shfl_xor(ss, off);
    __shared__ float wsum[4];
    if ((tid & 63) == 0) wsum[tid >> 6] = ss;
    __syncthreads();
    if (tid == 0) {
        float tot = wsum[0] + wsum[1] + wsum[2] + wsum[3];
        rn[row] = 1.0f / fmaxf(sqrtf(tot), 1e-12f);
    }
}

extern "C" void kernel_launch(void* const* d_in, const int* in_sizes, int n_in,
                              void* d_out, int out_size, void* d_ws, size_t ws_size,
                              hipStream_t stream) {
    const float* x      = (const float*)d_in[0];
    const float* conv_w = (const float*)d_in[1];
    const float* conv_b = (const float*)d_in[2];
    const float* mphi_w = (const float*)d_in[3];
    const float* mphi_b = (const float*)d_in[4];
    const float* wq_w   = (const float*)d_in[5];
    const float* wq_b   = (const float*)d_in[6];
    const float* wk_w   = (const float*)d_in[7];
    const float* wk_b   = (const float*)d_in[8];
    const float* wv_w   = (const float*)d_in[9];
    const float* wv_b   = (const float*)d_in[10];
    const float* wo_w   = (const float*)d_in[11];
    const float* wo_b   = (const float*)d_in[12];
    const float* wgz_w  = (const float*)d_in[13];
    const float* wgz_b  = (const float*)d_in[14];
    const float* kv_sc  = (const float*)d_in[15];
    const float* qk_sc  = (const float*)d_in[16];
    float* out = (float*)d_out;

    // ---- workspace layout (MB offsets), peak 100 MB ----
    char* p = (char*)d_ws;
    u16*  xp_h    = (u16*)p;                      // [0,4)   1026x1024 u16 (2.1MB)
    u16*  xp_l    = (u16*)(p + 4194304);          // [4,8)
    float* beff   = (float*)(p + 8388608);        // [8] 4KB
    u16*  wt_h    = (u16*)(p + 9437184);          // [9,15)  1024x3072 u16
    u16*  wt_l    = (u16*)(p + 15728640);         // [15,21)
    float* simG   = (float*)(p + 22020096);       // [21,24) small buffers
    float* gateG  = (float*)(p + 22085632);
    float* nlocp  = (float*)(p + 22151168);
    float* aggL   = (float*)(p + 22216704);
    float* rn     = (float*)(p + 22220800);
    u16*  wqkvT_h = (u16*)(p + 25165824);         // [24,30)
    u16*  wqkvT_l = (u16*)(p + 31457280);         // [30,36)
    u16*  woT_h   = (u16*)(p + 37748736);         // [36,38)
    u16*  woT_l   = (u16*)(p + 39845888);         // [38,40)
    float* qkvPart= (float*)(p + 41943040);       // [40,64)  2 x 12MB
    float* Ybuf   = (float*)(p + 41943040);       // [40,44)  after reduce_qkv
    u16*  y_h     = (u16*)(p + 46137344);         // [44,46)
    u16*  y_l     = (u16*)(p + 48234496);         // [46,48)
    float* woPart = (float*)(p + 50331648);       // [48,64)  4 x 4MB (after attn_out)
    float* g1Part = (float*)(p + 67108864);       // [64,96)  8 x 4MB
    float* qb     = (float*)(p + 67108864);       // [64,68)  after reduce_xt8
    float* kb     = (float*)(p + 71303168);       // [68,72)
    float* vb     = (float*)(p + 75497472);       // [72,76)
    float* Sloc   = (float*)(p + 79691776);       // [76,80)
    u16*  xt_h    = (u16*)(p + 100663296);        // [96,98)
    u16*  xt_l    = (u16*)(p + 102760448);        // [98,100)

    // x split (+ beff zero), conv⊗mphi weight fold
    xsplit<<<4104, 256, 0, stream>>>(x, xp_h, xp_l, beff);
    wtilde<<<dim3(32, 32), 256, 0, stream>>>(mphi_w, conv_w, conv_b, wt_h, wt_l, beff);

    // GEMM1 (conv-fused, K=3072, split-K=8) then reduce + biases + bf16 split
    gemm_conv3<<<dim3(8, 8, 8), 512, 0, stream>>>(xp_h, xp_l, wt_h, wt_l, g1Part);
    reduce_xt8<<<1024, 256, 0, stream>>>(g1Part, mphi_b, beff, xt_h, xt_l);

    // QKV + WO weight transposes
    wconv_t4<<<dim3(32, 32, 4), 256, 0, stream>>>(wq_w, wk_w, wv_w, wo_w,
            wqkvT_h, wqkvT_l, woT_h, woT_l);

    // QKV fused (N=3072, split-K=2); reduce adds bias + per-head norm
    gemm_bf16x3_128<<<dim3(24, 8, 2), 512, 0, stream>>>(xt_h, xt_l, wqkvT_h, wqkvT_l,
            qkvPart, 1024, 3072, 1024);
    reduce_qkv<<<1024, 256, 0, stream>>>(qkvPart, wq_b, wk_b, wv_b, qb, kb, vb);

    attn_local<<<dim3(NC, NH), 256, 0, stream>>>(qb, kb, vb, wgz_w, wgz_b, kv_sc, qk_sc,
                                                 simG, gateG, Sloc, nlocp, aggL);
    attn_out<<<dim3(NC, NH, 2), 256, 0, stream>>>(qb, kb, vb, simG, gateG, Sloc, nlocp, aggL,
                                                  kv_sc, Ybuf, y_h, y_l);
    rownorm<<<1024, 256, 0, stream>>>(Ybuf, rn);

    // WO (split-K=4); reduce applies rowscale + bias
    gemm_bf16x3_128<<<dim3(8, 8, 4), 512, 0, stream>>>(y_h, y_l, woT_h, woT_l,
            woPart, 1024, 1024, 1024);
    reduce_out<<<1024, 256, 0, stream>>>(woPart, 4, rn, wo_b, out);
}